// Round 3
// baseline (2090.684 us; speedup 1.0000x reference)
//
#include <hip/hip_runtime.h>
#include <math.h>

// Model_6150393168181 — fp32 baseline.
// out[b,n,p] depends only on flows->rms->SAGE x4->relu+rms->f, then
// Q=f@qsa^T, K=f@ksa^T, T[b,w,p,:] = S_w @ K[b,w], out = (1/sqrt(128)) Q·T^T.
// Coords path / cross-attn branch (qca,kca,s1w,cw*,cb*) are dead in the reference.

constexpr int KB = 32;

// ---------------- row normalize: mode 0 = L2-norm, 1 = L2-norm->relu->rms, 2 = rms ----------------
__global__ __launch_bounds__(256) void row_norm_k(const float* __restrict__ In,
                                                  float* __restrict__ Out,
                                                  int D, int mode) {
  long row = (long)blockIdx.x * 4 + (threadIdx.x >> 6);
  int lane = threadIdx.x & 63;
  const float* p = In + row * (long)D;
  float v[4] = {0.f, 0.f, 0.f, 0.f};
  int per = D >> 6;  // 2 or 4
  if (per == 2) {
    float2 t = *reinterpret_cast<const float2*>(p + lane * 2);
    v[0] = t.x; v[1] = t.y;
  } else {
    float4 t = *reinterpret_cast<const float4*>(p + lane * 4);
    v[0] = t.x; v[1] = t.y; v[2] = t.z; v[3] = t.w;
  }
  float ss = 0.f;
  #pragma unroll
  for (int i = 0; i < 4; ++i) ss += v[i] * v[i];
  ss += __shfl_xor(ss, 32); ss += __shfl_xor(ss, 16); ss += __shfl_xor(ss, 8);
  ss += __shfl_xor(ss, 4);  ss += __shfl_xor(ss, 2);  ss += __shfl_xor(ss, 1);
  float* q = Out + row * (long)D;
  float o[4];
  if (mode == 2) {
    float sc = rsqrtf(ss / (float)D);
    #pragma unroll
    for (int i = 0; i < 4; ++i) o[i] = v[i] * sc;
  } else {
    float inv = 1.0f / fmaxf(sqrtf(ss), 1e-12f);
    if (mode == 0) {
      #pragma unroll
      for (int i = 0; i < 4; ++i) o[i] = v[i] * inv;
    } else {
      float ss2 = 0.f;
      #pragma unroll
      for (int i = 0; i < 4; ++i) { o[i] = fmaxf(v[i] * inv, 0.f); ss2 += o[i] * o[i]; }
      ss2 += __shfl_xor(ss2, 32); ss2 += __shfl_xor(ss2, 16); ss2 += __shfl_xor(ss2, 8);
      ss2 += __shfl_xor(ss2, 4);  ss2 += __shfl_xor(ss2, 2);  ss2 += __shfl_xor(ss2, 1);
      float sc = sqrtf((float)D / ss2);
      #pragma unroll
      for (int i = 0; i < 4; ++i) o[i] *= sc;
    }
  }
  if (per == 2) {
    float2 t; t.x = o[0]; t.y = o[1];
    *reinterpret_cast<float2*>(q + lane * 2) = t;
  } else {
    float4 t; t.x = o[0]; t.y = o[1]; t.z = o[2]; t.w = o[3];
    *reinterpret_cast<float4*>(q + lane * 4) = t;
  }
}

// ---------------- agg[n] = (sum_{i<n} X[i]) / max(n,1), batch-0 rows only ----------------
__global__ void agg_prefix_k(const float* __restrict__ X, float* __restrict__ AGG, int IN) {
  int n = blockIdx.x;     // 0..127
  int c = threadIdx.x;    // 0..IN-1
  float s = 0.f;
  for (int i = 0; i < n; ++i) s += X[(long)i * IN + c];
  AGG[(long)n * IN + c] = s / (float)(n > 1 ? n : 1);
}

// ---------------- SALL[w][p][m] = s2w[p, m*8 + w] ----------------
__global__ void prep_sall_k(const float* __restrict__ s2w, float* __restrict__ S) {
  int e = blockIdx.x * 256 + threadIdx.x;        // 8*128*128 total
  int w = e >> 14, p = (e >> 7) & 127, m = e & 127;
  S[e] = s2w[p * 1024 + m * 8 + w];
}

// ---------------- generic tiled GEMM: C[r][c] = sum_k A[r][k] * Wrow[c][k] (+bias)*cscale ----
// TR rows per block, 128 cols per block. W layout: wkmaj=0 -> W[c][k] (ldw=row stride),
// wkmaj=1 -> W[k][c]. Optional second pass (A2,W2) accumulated for row-block 0 only (SAGE agg).
template <int TR>
__global__ __launch_bounds__(256) void gemm_tiled(
    const float* __restrict__ A, int lda, long aColOff,
    const float* __restrict__ W, int ldw, int wkmaj,
    const float* __restrict__ bias,
    const float* __restrict__ A2, const float* __restrict__ W2,
    float* __restrict__ C, int ldc, int coff,
    int K, float cscale,
    long bsA, long bsW, long bsC) {
  constexpr int RPT = TR / 16;
  __shared__ float As[TR][KB + 1];
  __shared__ float Ws[KB][133];
  int rb = blockIdx.x, cb = blockIdx.y, bz = blockIdx.z;
  int tid = threadIdx.x;
  int tx = tid & 15, ty = tid >> 4;
  float acc[RPT][8];
  #pragma unroll
  for (int i = 0; i < RPT; ++i)
    #pragma unroll
    for (int j = 0; j < 8; ++j) acc[i][j] = 0.f;

  const float* Abase = A + (long)bz * bsA + (long)cb * aColOff + (long)rb * TR * lda;
  const float* Wbase = W + (long)bz * bsW;

  for (int pass = 0; pass < 2; ++pass) {
    const float* Ap; const float* Wp;
    if (pass == 0) { Ap = Abase; Wp = Wbase; }
    else {
      if (A2 == nullptr || rb != 0) break;   // agg correction: rows 0..127 only
      Ap = A2; Wp = W2;
    }
    for (int kt = 0; kt < K; kt += KB) {
      __syncthreads();
      for (int e = tid; e < TR * KB; e += 256) {
        int r = e >> 5, k = e & 31;
        As[r][k] = Ap[(long)r * lda + kt + k];
      }
      if (!wkmaj) {
        for (int e = tid; e < 128 * KB; e += 256) {
          int c = e >> 5, k = e & 31;
          Ws[k][c] = Wp[(long)(cb * 128 + c) * ldw + kt + k];
        }
      } else {
        for (int e = tid; e < 128 * KB; e += 256) {
          int k = e >> 7, c = e & 127;
          Ws[k][c] = Wp[(long)(kt + k) * ldw + cb * 128 + c];
        }
      }
      __syncthreads();
      #pragma unroll
      for (int k = 0; k < KB; ++k) {
        float a[RPT], b[8];
        #pragma unroll
        for (int i = 0; i < RPT; ++i) a[i] = As[ty * RPT + i][k];
        #pragma unroll
        for (int j = 0; j < 8; ++j) b[j] = Ws[k][tx * 8 + j];
        #pragma unroll
        for (int i = 0; i < RPT; ++i)
          #pragma unroll
          for (int j = 0; j < 8; ++j) acc[i][j] += a[i] * b[j];
      }
    }
  }
  float bb[8];
  #pragma unroll
  for (int j = 0; j < 8; ++j) bb[j] = bias ? bias[cb * 128 + tx * 8 + j] : 0.f;
  #pragma unroll
  for (int i = 0; i < RPT; ++i) {
    long r = (long)rb * TR + ty * RPT + i;
    float* crow = C + (long)bz * bsC + r * ldc + coff + cb * 128 + tx * 8;
    float4 u, w4;
    u.x = (acc[i][0] + bb[0]) * cscale; u.y = (acc[i][1] + bb[1]) * cscale;
    u.z = (acc[i][2] + bb[2]) * cscale; u.w = (acc[i][3] + bb[3]) * cscale;
    w4.x = (acc[i][4] + bb[4]) * cscale; w4.y = (acc[i][5] + bb[5]) * cscale;
    w4.z = (acc[i][6] + bb[6]) * cscale; w4.w = (acc[i][7] + bb[7]) * cscale;
    *reinterpret_cast<float4*>(crow) = u;
    *reinterpret_cast<float4*>(crow + 4) = w4;
  }
}

extern "C" void kernel_launch(void* const* d_in, const int* in_sizes, int n_in,
                              void* d_out, int out_size, void* d_ws, size_t ws_size,
                              hipStream_t stream) {
  const float* flows = (const float*)d_in[0];
  const float* g1_wl = (const float*)d_in[10];
  const float* g1_bl = (const float*)d_in[11];
  const float* g1_wr = (const float*)d_in[12];
  const float* g2_wl = (const float*)d_in[13];
  const float* g2_bl = (const float*)d_in[14];
  const float* g2_wr = (const float*)d_in[15];
  const float* g3_wl = (const float*)d_in[16];
  const float* g3_bl = (const float*)d_in[17];
  const float* g3_wr = (const float*)d_in[18];
  const float* g4_wl = (const float*)d_in[19];
  const float* g4_bl = (const float*)d_in[20];
  const float* g4_wr = (const float*)d_in[21];
  const float* qsa   = (const float*)d_in[24];
  const float* ksa   = (const float*)d_in[25];
  const float* s2w   = (const float*)d_in[27];
  float* out = (float*)d_out;
  float* ws  = (float*)d_ws;

  // workspace layout (floats)
  float* XA   = ws;                                   // 32768*256
  float* XB   = XA + (size_t)32768 * 256;             // 32768*256
  float* AGG  = XB + (size_t)32768 * 256;             // 128*256
  float* SALL = AGG + 128 * 256;                      // 8*128*128
  float* QK   = SALL + 131072;                        // BC*128*2048

  size_t base  = (size_t)32768 * 256 * 2 + 128 * 256 + 131072;
  size_t avail = ws_size / sizeof(float);
  int BC = 256;
  while (BC > 1 && base + (size_t)BC * 262144 > avail) BC >>= 1;

  // f_in = rms(flows)
  row_norm_k<<<8192, 256, 0, stream>>>(flows, XA, 128, 2);

  // SAGE L1: 128 -> 128
  agg_prefix_k<<<128, 128, 0, stream>>>(XA, AGG, 128);
  gemm_tiled<128><<<dim3(256, 1, 1), 256, 0, stream>>>(XA, 128, 0, g1_wr, 128, 0, g1_bl,
                                                       AGG, g1_wl, XB, 128, 0, 128, 1.0f, 0, 0, 0);
  row_norm_k<<<8192, 256, 0, stream>>>(XB, XB, 128, 0);
  // SAGE L2: 128 -> 256
  agg_prefix_k<<<128, 128, 0, stream>>>(XB, AGG, 128);
  gemm_tiled<128><<<dim3(256, 2, 1), 256, 0, stream>>>(XB, 128, 0, g2_wr, 128, 0, g2_bl,
                                                       AGG, g2_wl, XA, 256, 0, 128, 1.0f, 0, 0, 0);
  row_norm_k<<<8192, 256, 0, stream>>>(XA, XA, 256, 0);
  // SAGE L3: 256 -> 128
  agg_prefix_k<<<128, 256, 0, stream>>>(XA, AGG, 256);
  gemm_tiled<128><<<dim3(256, 1, 1), 256, 0, stream>>>(XA, 256, 0, g3_wr, 256, 0, g3_bl,
                                                       AGG, g3_wl, XB, 128, 0, 256, 1.0f, 0, 0, 0);
  row_norm_k<<<8192, 256, 0, stream>>>(XB, XB, 128, 0);
  // SAGE L4: 128 -> 128, then relu+rms -> f (in XA)
  agg_prefix_k<<<128, 128, 0, stream>>>(XB, AGG, 128);
  gemm_tiled<128><<<dim3(256, 1, 1), 256, 0, stream>>>(XB, 128, 0, g4_wr, 128, 0, g4_bl,
                                                       AGG, g4_wl, XA, 128, 0, 128, 1.0f, 0, 0, 0);
  row_norm_k<<<8192, 256, 0, stream>>>(XA, XA, 128, 1);

  // reorder s2w -> SALL[w][p][m]
  prep_sall_k<<<512, 256, 0, stream>>>(s2w, SALL);

  const float inv_scale = 0.08838834764831845f;  // 1/sqrt(128)
  for (int c0 = 0; c0 < 256; c0 += BC) {
    const float* F = XA + (size_t)c0 * 16384;
    // Q half: cols [0,1024): Q[b,n, w*128+o]
    gemm_tiled<128><<<dim3(BC, 8, 1), 256, 0, stream>>>(F, 128, 0, qsa, 128, 0, nullptr,
                                                        nullptr, nullptr, QK, 2048, 0,
                                                        128, 1.0f, 0, 0, 0);
    // K half: cols [1024,2048)
    gemm_tiled<128><<<dim3(BC, 8, 1), 256, 0, stream>>>(F, 128, 0, ksa, 128, 0, nullptr,
                                                        nullptr, nullptr, QK, 2048, 1024,
                                                        128, 1.0f, 0, 0, 0);
    // T[b,w] = S_w @ K[b,w]  (in place over K half; one block owns one (b,w) tile)
    gemm_tiled<128><<<dim3(1, 8, BC), 256, 0, stream>>>(SALL, 128, 16384, QK + 1024, 2048, 1,
                                                        nullptr, nullptr, nullptr, QK, 2048, 1024,
                                                        128, 1.0f, 0, 262144, 262144);
    // out[b] = (1/sqrt(128)) * Q[b] @ T[b]^T
    gemm_tiled<64><<<dim3(2, 1, BC), 256, 0, stream>>>(QK, 2048, 0, QK + 1024, 2048, 0, nullptr,
                                                       nullptr, nullptr, out + (size_t)c0 * 16384,
                                                       128, 0, 1024, inv_scale,
                                                       262144, 262144, 16384);
  }
}

// Round 4
// 732.078 us; speedup vs baseline: 2.8558x; 2.8558x over previous
//
#include <hip/hip_runtime.h>
#include <math.h>

// Model_6150393168181 — SAGE fp32 + fused bf16-MFMA attention.
// out[b] = (1/sqrt(128)) * sum_w (f qsa_w^T) (S_w f ksa_w^T)^T, f = rms(relu(SAGE4(rms(flows)))).

constexpr int KB = 32;

typedef __attribute__((ext_vector_type(8))) short bf16x8;
typedef __attribute__((ext_vector_type(4))) float f32x4;

__device__ inline ushort f2b(float x) {
  unsigned u = __builtin_bit_cast(unsigned, x);
  unsigned r = (u + 0x7fffu + ((u >> 16) & 1u)) >> 16;
  return (ushort)r;
}

// ---------------- row normalize: mode 0 = L2, 1 = L2->relu->rms (bf16 out), 2 = rms ----------------
__global__ __launch_bounds__(256) void row_norm_k(const float* __restrict__ In,
                                                  float* __restrict__ Out,
                                                  ushort* __restrict__ OutB,
                                                  int D, int mode) {
  long row = (long)blockIdx.x * 4 + (threadIdx.x >> 6);
  int lane = threadIdx.x & 63;
  const float* p = In + row * (long)D;
  float v[4] = {0.f, 0.f, 0.f, 0.f};
  int per = D >> 6;  // 2 or 4
  if (per == 2) {
    float2 t = *reinterpret_cast<const float2*>(p + lane * 2);
    v[0] = t.x; v[1] = t.y;
  } else {
    float4 t = *reinterpret_cast<const float4*>(p + lane * 4);
    v[0] = t.x; v[1] = t.y; v[2] = t.z; v[3] = t.w;
  }
  float ss = 0.f;
  #pragma unroll
  for (int i = 0; i < 4; ++i) ss += v[i] * v[i];
  ss += __shfl_xor(ss, 32); ss += __shfl_xor(ss, 16); ss += __shfl_xor(ss, 8);
  ss += __shfl_xor(ss, 4);  ss += __shfl_xor(ss, 2);  ss += __shfl_xor(ss, 1);
  float o[4];
  if (mode == 2) {
    float sc = rsqrtf(ss / (float)D);
    #pragma unroll
    for (int i = 0; i < 4; ++i) o[i] = v[i] * sc;
  } else {
    float inv = 1.0f / fmaxf(sqrtf(ss), 1e-12f);
    if (mode == 0) {
      #pragma unroll
      for (int i = 0; i < 4; ++i) o[i] = v[i] * inv;
    } else {
      float ss2 = 0.f;
      #pragma unroll
      for (int i = 0; i < 4; ++i) { o[i] = fmaxf(v[i] * inv, 0.f); ss2 += o[i] * o[i]; }
      ss2 += __shfl_xor(ss2, 32); ss2 += __shfl_xor(ss2, 16); ss2 += __shfl_xor(ss2, 8);
      ss2 += __shfl_xor(ss2, 4);  ss2 += __shfl_xor(ss2, 2);  ss2 += __shfl_xor(ss2, 1);
      float sc = sqrtf((float)D / ss2);
      #pragma unroll
      for (int i = 0; i < 4; ++i) o[i] *= sc;
    }
  }
  if (OutB) {  // D==128, per==2: pack 2 bf16 into one uint
    unsigned pk = (unsigned)f2b(o[0]) | ((unsigned)f2b(o[1]) << 16);
    *reinterpret_cast<unsigned*>(OutB + row * (long)D + lane * 2) = pk;
    return;
  }
  float* q = Out + row * (long)D;
  if (per == 2) {
    float2 t; t.x = o[0]; t.y = o[1];
    *reinterpret_cast<float2*>(q + lane * 2) = t;
  } else {
    float4 t; t.x = o[0]; t.y = o[1]; t.z = o[2]; t.w = o[3];
    *reinterpret_cast<float4*>(q + lane * 4) = t;
  }
}

// ---------------- agg[n] = (sum_{i<n} X[i]) / max(n,1), batch-0 rows only ----------------
__global__ void agg_prefix_k(const float* __restrict__ X, float* __restrict__ AGG, int IN) {
  int n = blockIdx.x;
  int c = threadIdx.x;
  float s = 0.f;
  for (int i = 0; i < n; ++i) s += X[(long)i * IN + c];
  AGG[(long)n * IN + c] = s / (float)(n > 1 ? n : 1);
}

// ---------------- bf16 weight prep ----------------
__global__ void prep_qk_k(const float* __restrict__ q, const float* __restrict__ k,
                          ushort* __restrict__ Qb, ushort* __restrict__ Kb) {
  int e = blockIdx.x * 256 + threadIdx.x;  // 131072
  Qb[e] = f2b(q[e]);
  Kb[e] = f2b(k[e]);
}
__global__ void prep_s_k(const float* __restrict__ s2w, ushort* __restrict__ Sb) {
  int e = blockIdx.x * 256 + threadIdx.x;  // 131072: SB[w][p][m] = s2w[p][m*8+w]
  int w = e >> 14, p = (e >> 7) & 127, m = e & 127;
  Sb[e] = f2b(s2w[p * 1024 + m * 8 + w]);
}

// ---------------- generic tiled fp32 GEMM (SAGE path) ----------------
template <int TR>
__global__ __launch_bounds__(256) void gemm_tiled(
    const float* __restrict__ A, int lda,
    const float* __restrict__ W, int ldw,
    const float* __restrict__ bias,
    const float* __restrict__ A2, const float* __restrict__ W2,
    float* __restrict__ C, int ldc, int K) {
  constexpr int RPT = TR / 16;
  __shared__ float As[TR][KB + 1];
  __shared__ float Ws[KB][133];
  int rb = blockIdx.x, cb = blockIdx.y;
  int tid = threadIdx.x;
  int tx = tid & 15, ty = tid >> 4;
  float acc[RPT][8];
  #pragma unroll
  for (int i = 0; i < RPT; ++i)
    #pragma unroll
    for (int j = 0; j < 8; ++j) acc[i][j] = 0.f;

  const float* Abase = A + (long)rb * TR * lda;

  for (int pass = 0; pass < 2; ++pass) {
    const float* Ap; const float* Wp;
    if (pass == 0) { Ap = Abase; Wp = W; }
    else {
      if (A2 == nullptr || rb != 0) break;
      Ap = A2; Wp = W2;
    }
    for (int kt = 0; kt < K; kt += KB) {
      __syncthreads();
      for (int e = tid; e < TR * KB; e += 256) {
        int r = e >> 5, k = e & 31;
        As[r][k] = Ap[(long)r * lda + kt + k];
      }
      for (int e = tid; e < 128 * KB; e += 256) {
        int c = e >> 5, k = e & 31;
        Ws[k][c] = Wp[(long)(cb * 128 + c) * ldw + kt + k];
      }
      __syncthreads();
      #pragma unroll
      for (int k = 0; k < KB; ++k) {
        float a[RPT], b[8];
        #pragma unroll
        for (int i = 0; i < RPT; ++i) a[i] = As[ty * RPT + i][k];
        #pragma unroll
        for (int j = 0; j < 8; ++j) b[j] = Ws[k][tx * 8 + j];
        #pragma unroll
        for (int i = 0; i < RPT; ++i)
          #pragma unroll
          for (int j = 0; j < 8; ++j) acc[i][j] += a[i] * b[j];
      }
    }
  }
  float bb[8];
  #pragma unroll
  for (int j = 0; j < 8; ++j) bb[j] = bias ? bias[cb * 128 + tx * 8 + j] : 0.f;
  #pragma unroll
  for (int i = 0; i < RPT; ++i) {
    long r = (long)rb * TR + ty * RPT + i;
    float* crow = C + r * (long)ldc + cb * 128 + tx * 8;
    float4 u, w4;
    u.x = acc[i][0] + bb[0]; u.y = acc[i][1] + bb[1];
    u.z = acc[i][2] + bb[2]; u.w = acc[i][3] + bb[3];
    w4.x = acc[i][4] + bb[4]; w4.y = acc[i][5] + bb[5];
    w4.z = acc[i][6] + bb[6]; w4.w = acc[i][7] + bb[7];
    *reinterpret_cast<float4*>(crow) = u;
    *reinterpret_cast<float4*>(crow + 4) = w4;
  }
}

// ---------------- fused attention: one block per batch ----------------
// G1: Q=f@qsa_w^T  G2: K=f@ksa_w^T (->KT lds)  G3: T=S_w@K (->T lds)  G4: out+=Q@T^T
// MFMA 16x16x32 bf16. A-frag: row=l&15, k=8*(l>>4)+j. B-frag: col=l&15, k=8*(l>>4)+j.
// D-frag: col=l&15, row=4*(l>>4)+reg. LDS rows 256B, XOR-swizzle byte^=((row&7)<<4).
__global__ __launch_bounds__(256, 1) void attn_fused(
    const ushort* __restrict__ F, const ushort* __restrict__ QB,
    const ushort* __restrict__ KBf, const ushort* __restrict__ SB,
    float* __restrict__ Out) {
  __shared__ char lds[98304];
  char* Qlds = lds;
  char* KT   = lds + 32768;
  char* Tl   = lds + 65536;

  const int b = blockIdx.x;
  const int tid = threadIdx.x;
  const int l = tid & 63, wv = tid >> 6;
  const int wr = wv >> 1, wc = wv & 1;
  const int lr = l & 15, lg = l >> 4;

  const ushort* Fb = F + (size_t)b * 16384;

  // preload f A-fragments (reused for all 8 workers, G1 & G2)
  bf16x8 ff[4][4];
  #pragma unroll
  for (int i = 0; i < 4; ++i) {
    int n = (wr * 4 + i) * 16 + lr;
    #pragma unroll
    for (int ks = 0; ks < 4; ++ks)
      ff[i][ks] = *reinterpret_cast<const bf16x8*>(Fb + n * 128 + ks * 32 + lg * 8);
  }

  f32x4 oacc[4][4];
  #pragma unroll
  for (int i = 0; i < 4; ++i)
    #pragma unroll
    for (int j = 0; j < 4; ++j) oacc[i][j] = f32x4{0.f, 0.f, 0.f, 0.f};

  for (int w = 0; w < 8; ++w) {
    const ushort* qw = QB  + w * 16384;
    const ushort* kw = KBf + w * 16384;
    const ushort* sw = SB  + w * 16384;

    // ---- G1 + G2 ----
    #pragma unroll
    for (int j = 0; j < 4; ++j) {
      int o = (wc * 4 + j) * 16 + lr;
      bf16x8 bq[4], bk[4];
      #pragma unroll
      for (int ks = 0; ks < 4; ++ks) {
        bq[ks] = *reinterpret_cast<const bf16x8*>(qw + o * 128 + ks * 32 + lg * 8);
        bk[ks] = *reinterpret_cast<const bf16x8*>(kw + o * 128 + ks * 32 + lg * 8);
      }
      #pragma unroll
      for (int i = 0; i < 4; ++i) {
        f32x4 qa = {0.f, 0.f, 0.f, 0.f}, ka = {0.f, 0.f, 0.f, 0.f};
        #pragma unroll
        for (int ks = 0; ks < 4; ++ks) {
          qa = __builtin_amdgcn_mfma_f32_16x16x32_bf16(ff[i][ks], bq[ks], qa, 0, 0, 0);
          ka = __builtin_amdgcn_mfma_f32_16x16x32_bf16(ff[i][ks], bk[ks], ka, 0, 0, 0);
        }
        // Q[n][o] transpose-write (4 x b16)
        int nb = (wr * 4 + i) * 16 + lg * 4;
        #pragma unroll
        for (int r = 0; r < 4; ++r) {
          int n = nb + r;
          *reinterpret_cast<ushort*>(Qlds + n * 256 + ((o * 2) ^ ((n & 7) << 4))) = f2b(qa[r]);
        }
        // KT[o][m0..m0+3] packed b64 write
        uint2 pk;
        pk.x = (unsigned)f2b(ka[0]) | ((unsigned)f2b(ka[1]) << 16);
        pk.y = (unsigned)f2b(ka[2]) | ((unsigned)f2b(ka[3]) << 16);
        int m2 = ((wr * 4 + i) * 16 + lg * 4) * 2;
        *reinterpret_cast<uint2*>(KT + o * 256 + (m2 ^ ((o & 7) << 4))) = pk;
      }
    }
    __syncthreads();

    // ---- G3: T = S_w @ K ----
    bf16x8 as[4][4];
    #pragma unroll
    for (int i = 0; i < 4; ++i) {
      int p = (wr * 4 + i) * 16 + lr;
      #pragma unroll
      for (int ks = 0; ks < 4; ++ks)
        as[i][ks] = *reinterpret_cast<const bf16x8*>(sw + p * 128 + ks * 32 + lg * 8);
    }
    #pragma unroll
    for (int j = 0; j < 4; ++j) {
      int o = (wc * 4 + j) * 16 + lr;
      bf16x8 bkt[4];
      #pragma unroll
      for (int ks = 0; ks < 4; ++ks)
        bkt[ks] = *reinterpret_cast<const bf16x8*>(KT + o * 256 + ((ks * 64 + lg * 16) ^ ((o & 7) << 4)));
      #pragma unroll
      for (int i = 0; i < 4; ++i) {
        f32x4 ta = {0.f, 0.f, 0.f, 0.f};
        #pragma unroll
        for (int ks = 0; ks < 4; ++ks)
          ta = __builtin_amdgcn_mfma_f32_16x16x32_bf16(as[i][ks], bkt[ks], ta, 0, 0, 0);
        int pb = (wr * 4 + i) * 16 + lg * 4;
        #pragma unroll
        for (int r = 0; r < 4; ++r) {
          int p = pb + r;
          *reinterpret_cast<ushort*>(Tl + p * 256 + ((o * 2) ^ ((p & 7) << 4))) = f2b(ta[r]);
        }
      }
    }
    __syncthreads();

    // ---- G4: out += Q @ T^T ----
    bf16x8 aq[4][4];
    #pragma unroll
    for (int i = 0; i < 4; ++i) {
      int n = (wr * 4 + i) * 16 + lr;
      #pragma unroll
      for (int ks = 0; ks < 4; ++ks)
        aq[i][ks] = *reinterpret_cast<const bf16x8*>(Qlds + n * 256 + ((ks * 64 + lg * 16) ^ ((n & 7) << 4)));
    }
    #pragma unroll
    for (int j = 0; j < 4; ++j) {
      int p = (wc * 4 + j) * 16 + lr;
      bf16x8 bt[4];
      #pragma unroll
      for (int ks = 0; ks < 4; ++ks)
        bt[ks] = *reinterpret_cast<const bf16x8*>(Tl + p * 256 + ((ks * 64 + lg * 16) ^ ((p & 7) << 4)));
      #pragma unroll
      for (int i = 0; i < 4; ++i)
        #pragma unroll
        for (int ks = 0; ks < 4; ++ks)
          oacc[i][j] = __builtin_amdgcn_mfma_f32_16x16x32_bf16(aq[i][ks], bt[ks], oacc[i][j], 0, 0, 0);
    }
    __syncthreads();
  }

  const float inv_scale = 0.08838834764831845f;
  float* ob = Out + (size_t)b * 16384;
  #pragma unroll
  for (int i = 0; i < 4; ++i) {
    int nb = (wr * 4 + i) * 16 + lg * 4;
    #pragma unroll
    for (int j = 0; j < 4; ++j) {
      int p = (wc * 4 + j) * 16 + lr;
      #pragma unroll
      for (int r = 0; r < 4; ++r)
        ob[(nb + r) * 128 + p] = oacc[i][j][r] * inv_scale;
    }
  }
}

extern "C" void kernel_launch(void* const* d_in, const int* in_sizes, int n_in,
                              void* d_out, int out_size, void* d_ws, size_t ws_size,
                              hipStream_t stream) {
  const float* flows = (const float*)d_in[0];
  const float* g1_wl = (const float*)d_in[10];
  const float* g1_bl = (const float*)d_in[11];
  const float* g1_wr = (const float*)d_in[12];
  const float* g2_wl = (const float*)d_in[13];
  const float* g2_bl = (const float*)d_in[14];
  const float* g2_wr = (const float*)d_in[15];
  const float* g3_wl = (const float*)d_in[16];
  const float* g3_bl = (const float*)d_in[17];
  const float* g3_wr = (const float*)d_in[18];
  const float* g4_wl = (const float*)d_in[19];
  const float* g4_bl = (const float*)d_in[20];
  const float* g4_wr = (const float*)d_in[21];
  const float* qsa   = (const float*)d_in[24];
  const float* ksa   = (const float*)d_in[25];
  const float* s2w   = (const float*)d_in[27];
  float* out = (float*)d_out;
  char* wsb  = (char*)d_ws;

  // workspace layout (bytes)
  float*  XA   = (float*)(wsb);                        // 32768*256 f32
  float*  XB   = (float*)(wsb + 33554432);             // 32768*256 f32
  float*  AGG  = (float*)(wsb + 67108864);             // 128*256 f32
  ushort* FB16 = (ushort*)(wsb + 67239936);            // 32768*128 bf16
  ushort* QBg  = (ushort*)(wsb + 75628544);            // 8*128*128 bf16
  ushort* KBg  = (ushort*)(wsb + 75890688);
  ushort* SBg  = (ushort*)(wsb + 76152832);

  // weight prep (independent of SAGE chain)
  prep_qk_k<<<512, 256, 0, stream>>>(qsa, ksa, QBg, KBg);
  prep_s_k<<<512, 256, 0, stream>>>(s2w, SBg);

  // f_in = rms(flows)
  row_norm_k<<<8192, 256, 0, stream>>>(flows, XA, nullptr, 128, 2);

  // SAGE L1: 128 -> 128
  agg_prefix_k<<<128, 128, 0, stream>>>(XA, AGG, 128);
  gemm_tiled<128><<<dim3(256, 1), 256, 0, stream>>>(XA, 128, g1_wr, 128, g1_bl, AGG, g1_wl, XB, 128, 128);
  row_norm_k<<<8192, 256, 0, stream>>>(XB, XB, nullptr, 128, 0);
  // SAGE L2: 128 -> 256
  agg_prefix_k<<<128, 128, 0, stream>>>(XB, AGG, 128);
  gemm_tiled<128><<<dim3(256, 2), 256, 0, stream>>>(XB, 128, g2_wr, 128, g2_bl, AGG, g2_wl, XA, 256, 128);
  row_norm_k<<<8192, 256, 0, stream>>>(XA, XA, nullptr, 256, 0);
  // SAGE L3: 256 -> 128
  agg_prefix_k<<<128, 256, 0, stream>>>(XA, AGG, 256);
  gemm_tiled<128><<<dim3(256, 1), 256, 0, stream>>>(XA, 256, g3_wr, 256, g3_bl, AGG, g3_wl, XB, 128, 256);
  row_norm_k<<<8192, 256, 0, stream>>>(XB, XB, nullptr, 128, 0);
  // SAGE L4: 128 -> 128, then l2->relu->rms -> f (bf16)
  agg_prefix_k<<<128, 128, 0, stream>>>(XB, AGG, 128);
  gemm_tiled<128><<<dim3(256, 1), 256, 0, stream>>>(XB, 128, g4_wr, 128, g4_bl, AGG, g4_wl, XA, 128, 128);
  row_norm_k<<<8192, 256, 0, stream>>>(XA, nullptr, FB16, 128, 1);

  // fused attention
  attn_fused<<<256, 256, 0, stream>>>(FB16, QBg, KBg, SBg, out);
}

// Round 7
// 339.864 us; speedup vs baseline: 6.1515x; 2.1540x over previous
//
#include <hip/hip_runtime.h>
#include <math.h>

// Model_6150393168181 — fully bf16-MFMA pipeline.
// out[b] = (1/sqrt(128)) * sum_w (f qsa_w^T) (S_w f ksa_w^T)^T
// f = rms(relu(SAGE4(rms(flows)))); SAGE agg = exclusive-prefix-mean over batch-0 rows,
// expressed as corr_l = L @ (X_l @ wl_l^T), L[n][i] = (i<n)/max(n,1)  (MFMA-able).
// Row norms are folded into the next GEMM as per-row scales (s-fold), so X stays
// un-normalized bf16 in LDS between layers.

typedef __attribute__((ext_vector_type(8))) short bf16x8;
typedef __attribute__((ext_vector_type(4))) float f32x4;

__device__ inline ushort f2b(float x) {
  unsigned u = __builtin_bit_cast(unsigned, x);
  unsigned r = (u + 0x7fffu + ((u >> 16) & 1u)) >> 16;
  return (ushort)r;
}

// ---------------- prep: all bf16 weight conversions ----------------
__global__ __launch_bounds__(256) void prep_all_k(
    const float* __restrict__ qsa, const float* __restrict__ ksa, const float* __restrict__ s2w,
    const float* __restrict__ wl1, const float* __restrict__ wl2,
    const float* __restrict__ wl3, const float* __restrict__ wl4,
    const float* __restrict__ wr1, const float* __restrict__ wr2,
    const float* __restrict__ wr3, const float* __restrict__ wr4,
    ushort* __restrict__ QB, ushort* __restrict__ KB2, ushort* __restrict__ SB,
    ushort* __restrict__ WL, ushort* __restrict__ WR) {
  int i = blockIdx.x * 256 + threadIdx.x;
  if (i < 131072) {
    QB[i] = f2b(qsa[i]);
    KB2[i] = f2b(ksa[i]);
    int w = i >> 14, p = (i >> 7) & 127, m = i & 127;
    SB[i] = f2b(s2w[p * 1024 + m * 8 + w]);
    return;
  }
  i -= 131072;
  if (i < 98304) {
    float v, u;
    if      (i < 16384) { v = wl1[i];         u = wr1[i]; }
    else if (i < 49152) { v = wl2[i - 16384]; u = wr2[i - 16384]; }
    else if (i < 81920) { v = wl3[i - 49152]; u = wr3[i - 49152]; }
    else                { v = wl4[i - 81920]; u = wr4[i - 81920]; }
    WL[i] = f2b(v);
    WR[i] = f2b(u);
  }
}

// ---------------- stage flows rows (raw bf16 + rms scale) into LDS ----------------
__device__ inline void stage_flows(const float* __restrict__ flows, int blk,
                                   char* Xt, float* sArr, int wv, int lane) {
  for (int r = 0; r < 32; ++r) {
    int row = wv * 32 + r;
    const float2 v = *reinterpret_cast<const float2*>(
        flows + ((size_t)blk * 128 + row) * 128 + lane * 2);
    float ss = v.x * v.x + v.y * v.y;
    ss += __shfl_xor(ss, 32); ss += __shfl_xor(ss, 16); ss += __shfl_xor(ss, 8);
    ss += __shfl_xor(ss, 4);  ss += __shfl_xor(ss, 2);  ss += __shfl_xor(ss, 1);
    unsigned pk = (unsigned)f2b(v.x) | ((unsigned)f2b(v.y) << 16);
    *reinterpret_cast<unsigned*>(Xt + row * 256 + ((lane * 4) ^ ((row & 7) << 4))) = pk;
    if (lane == 0) sArr[row] = rsqrtf(ss * (1.0f / 128.0f));
  }
}

// ---------------- mid SAGE layer: y = s.x@Wr^T + b (+corr), store bf16 + new scale ----------------
template <int K, int N>
__device__ inline void sage_layer_mid(char* Xt, const float* sP, float* sN,
                                      const ushort* __restrict__ Wr,
                                      const float* __restrict__ bias,
                                      const float* __restrict__ corr, bool useCorr,
                                      int wv, int lr, int lg) {
  __syncthreads();
  bf16x8 a[2][K / 32];
  float sr[2][4];
  #pragma unroll
  for (int m = 0; m < 2; ++m) {
    int rowA = wv * 32 + m * 16 + lr;
    #pragma unroll
    for (int ks = 0; ks < K / 32; ++ks)
      a[m][ks] = *reinterpret_cast<const bf16x8*>(
          Xt + rowA * (K * 2) + ((ks * 64 + lg * 16) ^ ((rowA & 7) << 4)));
    #pragma unroll
    for (int rr = 0; rr < 4; ++rr) sr[m][rr] = sP[wv * 32 + m * 16 + 4 * lg + rr];
  }
  __syncthreads();
  float ssq[2][4] = {{0.f, 0.f, 0.f, 0.f}, {0.f, 0.f, 0.f, 0.f}};
  #pragma unroll
  for (int nt = 0; nt < N / 16; ++nt) {
    int col = nt * 16 + lr;
    bf16x8 b[K / 32];
    #pragma unroll
    for (int ks = 0; ks < K / 32; ++ks)
      b[ks] = *reinterpret_cast<const bf16x8*>(Wr + col * K + ks * 32 + lg * 8);
    f32x4 acc[2] = {{0.f, 0.f, 0.f, 0.f}, {0.f, 0.f, 0.f, 0.f}};
    #pragma unroll
    for (int ks = 0; ks < K / 32; ++ks) {
      acc[0] = __builtin_amdgcn_mfma_f32_16x16x32_bf16(a[0][ks], b[ks], acc[0], 0, 0, 0);
      acc[1] = __builtin_amdgcn_mfma_f32_16x16x32_bf16(a[1][ks], b[ks], acc[1], 0, 0, 0);
    }
    float bb = bias[col];
    #pragma unroll
    for (int m = 0; m < 2; ++m)
      #pragma unroll
      for (int rr = 0; rr < 4; ++rr) {
        int row = wv * 32 + m * 16 + 4 * lg + rr;
        float y = acc[m][rr] * sr[m][rr] + bb;
        if (useCorr) y += corr[row * N + col];
        *reinterpret_cast<ushort*>(Xt + row * (N * 2) + ((col * 2) ^ ((row & 7) << 4))) = f2b(y);
        ssq[m][rr] += y * y;
      }
  }
  #pragma unroll
  for (int m = 0; m < 2; ++m)
    #pragma unroll
    for (int rr = 0; rr < 4; ++rr) {
      float ss = ssq[m][rr];
      ss += __shfl_xor(ss, 1); ss += __shfl_xor(ss, 2);
      ss += __shfl_xor(ss, 4); ss += __shfl_xor(ss, 8);
      if (lr == 0) sN[wv * 32 + m * 16 + 4 * lg + rr] = 1.0f / fmaxf(sqrtf(ss), 1e-12f);
    }
}

// ---------------- last SAGE layer: y -> L2norm -> relu -> rms -> F (global bf16) ----------------
__device__ inline void sage_layer_last(char* Xt, const float* sP,
                                       const ushort* __restrict__ Wr,
                                       const float* __restrict__ bias,
                                       const float* __restrict__ corr, bool useCorr,
                                       int wv, int lr, int lg,
                                       ushort* __restrict__ Fg, int blk) {
  __syncthreads();
  bf16x8 a[2][4];
  float sr[2][4];
  #pragma unroll
  for (int m = 0; m < 2; ++m) {
    int rowA = wv * 32 + m * 16 + lr;
    #pragma unroll
    for (int ks = 0; ks < 4; ++ks)
      a[m][ks] = *reinterpret_cast<const bf16x8*>(
          Xt + rowA * 256 + ((ks * 64 + lg * 16) ^ ((rowA & 7) << 4)));
    #pragma unroll
    for (int rr = 0; rr < 4; ++rr) sr[m][rr] = sP[wv * 32 + m * 16 + 4 * lg + rr];
  }
  __syncthreads();
  float yreg[8][2][4];
  float ssq[2][4] = {{0.f, 0.f, 0.f, 0.f}, {0.f, 0.f, 0.f, 0.f}};
  #pragma unroll
  for (int nt = 0; nt < 8; ++nt) {
    int col = nt * 16 + lr;
    bf16x8 b[4];
    #pragma unroll
    for (int ks = 0; ks < 4; ++ks)
      b[ks] = *reinterpret_cast<const bf16x8*>(Wr + col * 128 + ks * 32 + lg * 8);
    f32x4 acc[2] = {{0.f, 0.f, 0.f, 0.f}, {0.f, 0.f, 0.f, 0.f}};
    #pragma unroll
    for (int ks = 0; ks < 4; ++ks) {
      acc[0] = __builtin_amdgcn_mfma_f32_16x16x32_bf16(a[0][ks], b[ks], acc[0], 0, 0, 0);
      acc[1] = __builtin_amdgcn_mfma_f32_16x16x32_bf16(a[1][ks], b[ks], acc[1], 0, 0, 0);
    }
    float bb = bias[col];
    #pragma unroll
    for (int m = 0; m < 2; ++m)
      #pragma unroll
      for (int rr = 0; rr < 4; ++rr) {
        int row = wv * 32 + m * 16 + 4 * lg + rr;
        float y = acc[m][rr] * sr[m][rr] + bb;
        if (useCorr) y += corr[row * 128 + col];
        yreg[nt][m][rr] = y;
        ssq[m][rr] += y * y;
      }
  }
  float inv[2][4];
  #pragma unroll
  for (int m = 0; m < 2; ++m)
    #pragma unroll
    for (int rr = 0; rr < 4; ++rr) {
      float ss = ssq[m][rr];
      ss += __shfl_xor(ss, 1); ss += __shfl_xor(ss, 2);
      ss += __shfl_xor(ss, 4); ss += __shfl_xor(ss, 8);
      inv[m][rr] = 1.0f / fmaxf(sqrtf(ss), 1e-12f);
    }
  float ss2[2][4] = {{0.f, 0.f, 0.f, 0.f}, {0.f, 0.f, 0.f, 0.f}};
  #pragma unroll
  for (int nt = 0; nt < 8; ++nt)
    #pragma unroll
    for (int m = 0; m < 2; ++m)
      #pragma unroll
      for (int rr = 0; rr < 4; ++rr) {
        float v = fmaxf(yreg[nt][m][rr] * inv[m][rr], 0.f);
        yreg[nt][m][rr] = v;
        ss2[m][rr] += v * v;
      }
  float sc[2][4];
  #pragma unroll
  for (int m = 0; m < 2; ++m)
    #pragma unroll
    for (int rr = 0; rr < 4; ++rr) {
      float ss = ss2[m][rr];
      ss += __shfl_xor(ss, 1); ss += __shfl_xor(ss, 2);
      ss += __shfl_xor(ss, 4); ss += __shfl_xor(ss, 8);
      sc[m][rr] = sqrtf(128.0f / fmaxf(ss, 1e-20f));
    }
  #pragma unroll
  for (int nt = 0; nt < 8; ++nt)
    #pragma unroll
    for (int m = 0; m < 2; ++m)
      #pragma unroll
      for (int rr = 0; rr < 4; ++rr) {
        int row = wv * 32 + m * 16 + 4 * lg + rr;
        Fg[((size_t)blk * 128 + row) * 128 + nt * 16 + lr] = f2b(yreg[nt][m][rr] * sc[m][rr]);
      }
}

// ---------------- K2: fused SAGE over all 32768 rows ----------------
__global__ __launch_bounds__(256, 2) void sage_fused(
    const float* __restrict__ flows, const ushort* __restrict__ WR,
    const float* __restrict__ bl1, const float* __restrict__ bl2,
    const float* __restrict__ bl3, const float* __restrict__ bl4,
    const float* __restrict__ C1, const float* __restrict__ C2,
    const float* __restrict__ C3, const float* __restrict__ C4,
    ushort* __restrict__ Fg) {
  __shared__ char Xt[65536];
  __shared__ float sA[128], sB[128];
  int blk = blockIdx.x, tid = threadIdx.x;
  int lane = tid & 63, wv = tid >> 6, lr = lane & 15, lg = lane >> 4;
  stage_flows(flows, blk, Xt, sA, wv, lane);
  bool c = (blk == 0);
  sage_layer_mid<128, 128>(Xt, sA, sB, WR + 0,     bl1, C1, c, wv, lr, lg);
  sage_layer_mid<128, 256>(Xt, sB, sA, WR + 16384, bl2, C2, c, wv, lr, lg);
  sage_layer_mid<256, 128>(Xt, sA, sB, WR + 49152, bl3, C3, c, wv, lr, lg);
  sage_layer_last(Xt, sB, WR + 81920, bl4, C4, c, wv, lr, lg, Fg, blk);
}

// ---------------- K1: batch-0 chain -> corr tables ----------------
// corr_l = L @ (s-folded X_l @ wl_l^T), L[n][i] = (i<n)/max(n,1) built in-register.
template <int K, int N, bool CORRONLY>
__device__ inline void chain_layer(char* Xt, char* C0T, const float* sP, float* sN,
                                   const ushort* __restrict__ Wl, const ushort* __restrict__ Wr,
                                   const float* __restrict__ bias, float* __restrict__ Cg,
                                   int wv, int lr, int lg) {
  __syncthreads();
  bf16x8 a[2][K / 32];
  float sr[2][4];
  #pragma unroll
  for (int m = 0; m < 2; ++m) {
    int rowA = wv * 32 + m * 16 + lr;
    #pragma unroll
    for (int ks = 0; ks < K / 32; ++ks)
      a[m][ks] = *reinterpret_cast<const bf16x8*>(
          Xt + rowA * (K * 2) + ((ks * 64 + lg * 16) ^ ((rowA & 7) << 4)));
    #pragma unroll
    for (int rr = 0; rr < 4; ++rr) sr[m][rr] = sP[wv * 32 + m * 16 + 4 * lg + rr];
  }
  __syncthreads();
  // pass 1: C0 = s.X @ Wl^T -> C0T[col][row] bf16 (transposed, swizzled)
  #pragma unroll
  for (int nt = 0; nt < N / 16; ++nt) {
    int col = nt * 16 + lr;
    bf16x8 b[K / 32];
    #pragma unroll
    for (int ks = 0; ks < K / 32; ++ks)
      b[ks] = *reinterpret_cast<const bf16x8*>(Wl + col * K + ks * 32 + lg * 8);
    f32x4 acc[2] = {{0.f, 0.f, 0.f, 0.f}, {0.f, 0.f, 0.f, 0.f}};
    #pragma unroll
    for (int ks = 0; ks < K / 32; ++ks) {
      acc[0] = __builtin_amdgcn_mfma_f32_16x16x32_bf16(a[0][ks], b[ks], acc[0], 0, 0, 0);
      acc[1] = __builtin_amdgcn_mfma_f32_16x16x32_bf16(a[1][ks], b[ks], acc[1], 0, 0, 0);
    }
    #pragma unroll
    for (int m = 0; m < 2; ++m)
      #pragma unroll
      for (int rr = 0; rr < 4; ++rr) {
        int row = wv * 32 + m * 16 + 4 * lg + rr;
        *reinterpret_cast<ushort*>(C0T + col * 256 + ((row * 2) ^ ((col & 7) << 4))) =
            f2b(acc[m][rr] * sr[m][rr]);
      }
  }
  __syncthreads();
  // build L A-fragments
  bf16x8 aL[2][4];
  #pragma unroll
  for (int m = 0; m < 2; ++m) {
    int rowL = wv * 32 + m * 16 + lr;
    ushort iv = f2b(1.0f / (float)(rowL > 1 ? rowL : 1));
    #pragma unroll
    for (int ks = 0; ks < 4; ++ks)
      #pragma unroll
      for (int j = 0; j < 8; ++j) {
        int k = ks * 32 + lg * 8 + j;
        aL[m][ks][j] = (short)((k < rowL) ? iv : 0);
      }
  }
  // pass 2: CORR = L @ C0 (write global); y = s.X @ Wr^T + b + CORR -> Xt
  float ssq[2][4] = {{0.f, 0.f, 0.f, 0.f}, {0.f, 0.f, 0.f, 0.f}};
  #pragma unroll
  for (int nt = 0; nt < N / 16; ++nt) {
    int col = nt * 16 + lr;
    bf16x8 bc[4];
    #pragma unroll
    for (int ks = 0; ks < 4; ++ks)
      bc[ks] = *reinterpret_cast<const bf16x8*>(
          C0T + col * 256 + ((ks * 64 + lg * 16) ^ ((col & 7) << 4)));
    f32x4 cacc[2] = {{0.f, 0.f, 0.f, 0.f}, {0.f, 0.f, 0.f, 0.f}};
    #pragma unroll
    for (int ks = 0; ks < 4; ++ks) {
      cacc[0] = __builtin_amdgcn_mfma_f32_16x16x32_bf16(aL[0][ks], bc[ks], cacc[0], 0, 0, 0);
      cacc[1] = __builtin_amdgcn_mfma_f32_16x16x32_bf16(aL[1][ks], bc[ks], cacc[1], 0, 0, 0);
    }
    #pragma unroll
    for (int m = 0; m < 2; ++m)
      #pragma unroll
      for (int rr = 0; rr < 4; ++rr) {
        int row = wv * 32 + m * 16 + 4 * lg + rr;
        Cg[row * N + col] = cacc[m][rr];
      }
    if (!CORRONLY) {
      bf16x8 b[K / 32];
      #pragma unroll
      for (int ks = 0; ks < K / 32; ++ks)
        b[ks] = *reinterpret_cast<const bf16x8*>(Wr + col * K + ks * 32 + lg * 8);
      f32x4 acc[2] = {{0.f, 0.f, 0.f, 0.f}, {0.f, 0.f, 0.f, 0.f}};
      #pragma unroll
      for (int ks = 0; ks < K / 32; ++ks) {
        acc[0] = __builtin_amdgcn_mfma_f32_16x16x32_bf16(a[0][ks], b[ks], acc[0], 0, 0, 0);
        acc[1] = __builtin_amdgcn_mfma_f32_16x16x32_bf16(a[1][ks], b[ks], acc[1], 0, 0, 0);
      }
      float bb = bias[col];
      #pragma unroll
      for (int m = 0; m < 2; ++m)
        #pragma unroll
        for (int rr = 0; rr < 4; ++rr) {
          int row = wv * 32 + m * 16 + 4 * lg + rr;
          float y = acc[m][rr] * sr[m][rr] + bb + cacc[m][rr];
          *reinterpret_cast<ushort*>(Xt + row * (N * 2) + ((col * 2) ^ ((row & 7) << 4))) = f2b(y);
          ssq[m][rr] += y * y;
        }
    }
  }
  if (!CORRONLY) {
    #pragma unroll
    for (int m = 0; m < 2; ++m)
      #pragma unroll
      for (int rr = 0; rr < 4; ++rr) {
        float ss = ssq[m][rr];
        ss += __shfl_xor(ss, 1); ss += __shfl_xor(ss, 2);
        ss += __shfl_xor(ss, 4); ss += __shfl_xor(ss, 8);
        if (lr == 0) sN[wv * 32 + m * 16 + 4 * lg + rr] = 1.0f / fmaxf(sqrtf(ss), 1e-12f);
      }
  }
}

__global__ __launch_bounds__(256, 1) void chain0_k(
    const float* __restrict__ flows, const ushort* __restrict__ WL, const ushort* __restrict__ WR,
    const float* __restrict__ bl1, const float* __restrict__ bl2, const float* __restrict__ bl3,
    float* __restrict__ C1, float* __restrict__ C2, float* __restrict__ C3, float* __restrict__ C4) {
  __shared__ char Xt[65536];
  __shared__ char C0T[65536];
  __shared__ float sA[128], sB[128];
  int tid = threadIdx.x;
  int lane = tid & 63, wv = tid >> 6, lr = lane & 15, lg = lane >> 4;
  stage_flows(flows, 0, Xt, sA, wv, lane);
  chain_layer<128, 128, false>(Xt, C0T, sA, sB, WL + 0,     WR + 0,     bl1, C1, wv, lr, lg);
  chain_layer<128, 256, false>(Xt, C0T, sB, sA, WL + 16384, WR + 16384, bl2, C2, wv, lr, lg);
  chain_layer<256, 128, false>(Xt, C0T, sA, sB, WL + 49152, WR + 49152, bl3, C3, wv, lr, lg);
  chain_layer<128, 128, true >(Xt, C0T, sB, sA, WL + 81920, WR + 81920, nullptr, C4, wv, lr, lg);
}

// ---------------- fused attention: one block per batch (unchanged, verified) ----------------
__global__ __launch_bounds__(256, 1) void attn_fused(
    const ushort* __restrict__ F, const ushort* __restrict__ QB,
    const ushort* __restrict__ KBf, const ushort* __restrict__ SB,
    float* __restrict__ Out) {
  __shared__ char lds[98304];
  char* Qlds = lds;
  char* KT   = lds + 32768;
  char* Tl   = lds + 65536;

  const int b = blockIdx.x;
  const int tid = threadIdx.x;
  const int l = tid & 63, wv = tid >> 6;
  const int wr = wv >> 1, wc = wv & 1;
  const int lr = l & 15, lg = l >> 4;

  const ushort* Fb = F + (size_t)b * 16384;

  bf16x8 ff[4][4];
  #pragma unroll
  for (int i = 0; i < 4; ++i) {
    int n = (wr * 4 + i) * 16 + lr;
    #pragma unroll
    for (int ks = 0; ks < 4; ++ks)
      ff[i][ks] = *reinterpret_cast<const bf16x8*>(Fb + n * 128 + ks * 32 + lg * 8);
  }

  f32x4 oacc[4][4];
  #pragma unroll
  for (int i = 0; i < 4; ++i)
    #pragma unroll
    for (int j = 0; j < 4; ++j) oacc[i][j] = f32x4{0.f, 0.f, 0.f, 0.f};

  for (int w = 0; w < 8; ++w) {
    const ushort* qw = QB  + w * 16384;
    const ushort* kw = KBf + w * 16384;
    const ushort* sw = SB  + w * 16384;

    #pragma unroll
    for (int j = 0; j < 4; ++j) {
      int o = (wc * 4 + j) * 16 + lr;
      bf16x8 bq[4], bk[4];
      #pragma unroll
      for (int ks = 0; ks < 4; ++ks) {
        bq[ks] = *reinterpret_cast<const bf16x8*>(qw + o * 128 + ks * 32 + lg * 8);
        bk[ks] = *reinterpret_cast<const bf16x8*>(kw + o * 128 + ks * 32 + lg * 8);
      }
      #pragma unroll
      for (int i = 0; i < 4; ++i) {
        f32x4 qa = {0.f, 0.f, 0.f, 0.f}, ka = {0.f, 0.f, 0.f, 0.f};
        #pragma unroll
        for (int ks = 0; ks < 4; ++ks) {
          qa = __builtin_amdgcn_mfma_f32_16x16x32_bf16(ff[i][ks], bq[ks], qa, 0, 0, 0);
          ka = __builtin_amdgcn_mfma_f32_16x16x32_bf16(ff[i][ks], bk[ks], ka, 0, 0, 0);
        }
        int nb = (wr * 4 + i) * 16 + lg * 4;
        #pragma unroll
        for (int r = 0; r < 4; ++r) {
          int n = nb + r;
          *reinterpret_cast<ushort*>(Qlds + n * 256 + ((o * 2) ^ ((n & 7) << 4))) = f2b(qa[r]);
        }
        uint2 pk;
        pk.x = (unsigned)f2b(ka[0]) | ((unsigned)f2b(ka[1]) << 16);
        pk.y = (unsigned)f2b(ka[2]) | ((unsigned)f2b(ka[3]) << 16);
        int m2 = ((wr * 4 + i) * 16 + lg * 4) * 2;
        *reinterpret_cast<uint2*>(KT + o * 256 + (m2 ^ ((o & 7) << 4))) = pk;
      }
    }
    __syncthreads();

    bf16x8 as[4][4];
    #pragma unroll
    for (int i = 0; i < 4; ++i) {
      int p = (wr * 4 + i) * 16 + lr;
      #pragma unroll
      for (int ks = 0; ks < 4; ++ks)
        as[i][ks] = *reinterpret_cast<const bf16x8*>(sw + p * 128 + ks * 32 + lg * 8);
    }
    #pragma unroll
    for (int j = 0; j < 4; ++j) {
      int o = (wc * 4 + j) * 16 + lr;
      bf16x8 bkt[4];
      #pragma unroll
      for (int ks = 0; ks < 4; ++ks)
        bkt[ks] = *reinterpret_cast<const bf16x8*>(KT + o * 256 + ((ks * 64 + lg * 16) ^ ((o & 7) << 4)));
      #pragma unroll
      for (int i = 0; i < 4; ++i) {
        f32x4 ta = {0.f, 0.f, 0.f, 0.f};
        #pragma unroll
        for (int ks = 0; ks < 4; ++ks)
          ta = __builtin_amdgcn_mfma_f32_16x16x32_bf16(as[i][ks], bkt[ks], ta, 0, 0, 0);
        int pb = (wr * 4 + i) * 16 + lg * 4;
        #pragma unroll
        for (int r = 0; r < 4; ++r) {
          int p = pb + r;
          *reinterpret_cast<ushort*>(Tl + p * 256 + ((o * 2) ^ ((p & 7) << 4))) = f2b(ta[r]);
        }
      }
    }
    __syncthreads();

    bf16x8 aq[4][4];
    #pragma unroll
    for (int i = 0; i < 4; ++i) {
      int n = (wr * 4 + i) * 16 + lr;
      #pragma unroll
      for (int ks = 0; ks < 4; ++ks)
        aq[i][ks] = *reinterpret_cast<const bf16x8*>(Qlds + n * 256 + ((ks * 64 + lg * 16) ^ ((n & 7) << 4)));
    }
    #pragma unroll
    for (int j = 0; j < 4; ++j) {
      int p = (wc * 4 + j) * 16 + lr;
      bf16x8 bt[4];
      #pragma unroll
      for (int ks = 0; ks < 4; ++ks)
        bt[ks] = *reinterpret_cast<const bf16x8*>(Tl + p * 256 + ((ks * 64 + lg * 16) ^ ((p & 7) << 4)));
      #pragma unroll
      for (int i = 0; i < 4; ++i)
        #pragma unroll
        for (int ks = 0; ks < 4; ++ks)
          oacc[i][j] = __builtin_amdgcn_mfma_f32_16x16x32_bf16(aq[i][ks], bt[ks], oacc[i][j], 0, 0, 0);
    }
    __syncthreads();
  }

  const float inv_scale = 0.08838834764831845f;
  float* ob = Out + (size_t)b * 16384;
  #pragma unroll
  for (int i = 0; i < 4; ++i) {
    int nb = (wr * 4 + i) * 16 + lg * 4;
    #pragma unroll
    for (int j = 0; j < 4; ++j) {
      int p = (wc * 4 + j) * 16 + lr;
      #pragma unroll
      for (int r = 0; r < 4; ++r)
        ob[(nb + r) * 128 + p] = oacc[i][j][r] * inv_scale;
    }
  }
}

extern "C" void kernel_launch(void* const* d_in, const int* in_sizes, int n_in,
                              void* d_out, int out_size, void* d_ws, size_t ws_size,
                              hipStream_t stream) {
  const float* flows = (const float*)d_in[0];
  const float* g1_wl = (const float*)d_in[10];
  const float* g1_bl = (const float*)d_in[11];
  const float* g1_wr = (const float*)d_in[12];
  const float* g2_wl = (const float*)d_in[13];
  const float* g2_bl = (const float*)d_in[14];
  const float* g2_wr = (const float*)d_in[15];
  const float* g3_wl = (const float*)d_in[16];
  const float* g3_bl = (const float*)d_in[17];
  const float* g3_wr = (const float*)d_in[18];
  const float* g4_wl = (const float*)d_in[19];
  const float* g4_bl = (const float*)d_in[20];
  const float* g4_wr = (const float*)d_in[21];
  const float* qsa   = (const float*)d_in[24];
  const float* ksa   = (const float*)d_in[25];
  const float* s2w   = (const float*)d_in[27];
  float* out = (float*)d_out;
  char* wsb  = (char*)d_ws;

  // workspace layout (bytes)
  ushort* FB16 = (ushort*)(wsb);                 // 32768*128 bf16 = 8388608
  ushort* QB   = (ushort*)(wsb + 8388608);       // 131072 bf16
  ushort* KB2  = (ushort*)(wsb + 8650752);
  ushort* SB   = (ushort*)(wsb + 8912896);
  ushort* WL   = (ushort*)(wsb + 9175040);       // 98304 bf16
  ushort* WR   = (ushort*)(wsb + 9371648);
  float*  C1   = (float*)(wsb + 9568256);        // 128*128 f32
  float*  C2   = (float*)(wsb + 9633792);        // 128*256 f32
  float*  C3   = (float*)(wsb + 9764864);        // 128*128 f32
  float*  C4   = (float*)(wsb + 9830400);        // 128*128 f32

  prep_all_k<<<896, 256, 0, stream>>>(qsa, ksa, s2w,
                                      g1_wl, g2_wl, g3_wl, g4_wl,
                                      g1_wr, g2_wr, g3_wr, g4_wr,
                                      QB, KB2, SB, WL, WR);
  chain0_k<<<1, 256, 0, stream>>>(flows, WL, WR, g1_bl, g2_bl, g3_bl, C1, C2, C3, C4);
  sage_fused<<<256, 256, 0, stream>>>(flows, WR, g1_bl, g2_bl, g3_bl, g4_bl,
                                      C1, C2, C3, C4, FB16);
  attn_fused<<<256, 256, 0, stream>>>(FB16, QB, KB2, SB, out);
}

// Round 8
// 297.213 us; speedup vs baseline: 7.0343x; 1.1435x over previous
//
#include <hip/hip_runtime.h>
#include <math.h>

// Model_6150393168181 — fully bf16-MFMA pipeline.
// out[b] = (1/sqrt(128)) * sum_w (f qsa_w^T) (S_w f ksa_w^T)^T
// f = rms(relu(SAGE4(rms(flows)))); SAGE agg = exclusive-prefix-mean over batch-0 rows,
// corr_l = L @ (X_l @ wl_l^T), L[n][i] = (i<n)/max(n,1)  (MFMA-able, chain0_k).
// sage_fused: 512 blocks x 64 rows, 2 blocks/CU, pipelined float4 staging.

typedef __attribute__((ext_vector_type(8))) short bf16x8;
typedef __attribute__((ext_vector_type(4))) float f32x4;

__device__ inline ushort f2b(float x) {
  unsigned u = __builtin_bit_cast(unsigned, x);
  unsigned r = (u + 0x7fffu + ((u >> 16) & 1u)) >> 16;
  return (ushort)r;
}

// ---------------- prep: all bf16 weight conversions ----------------
__global__ __launch_bounds__(256) void prep_all_k(
    const float* __restrict__ qsa, const float* __restrict__ ksa, const float* __restrict__ s2w,
    const float* __restrict__ wl1, const float* __restrict__ wl2,
    const float* __restrict__ wl3, const float* __restrict__ wl4,
    const float* __restrict__ wr1, const float* __restrict__ wr2,
    const float* __restrict__ wr3, const float* __restrict__ wr4,
    ushort* __restrict__ QB, ushort* __restrict__ KB2, ushort* __restrict__ SB,
    ushort* __restrict__ WL, ushort* __restrict__ WR) {
  int i = blockIdx.x * 256 + threadIdx.x;
  if (i < 131072) {
    QB[i] = f2b(qsa[i]);
    KB2[i] = f2b(ksa[i]);
    int w = i >> 14, p = (i >> 7) & 127, m = i & 127;
    SB[i] = f2b(s2w[p * 1024 + m * 8 + w]);
    return;
  }
  i -= 131072;
  if (i < 98304) {
    float v, u;
    if      (i < 16384) { v = wl1[i];         u = wr1[i]; }
    else if (i < 49152) { v = wl2[i - 16384]; u = wr2[i - 16384]; }
    else if (i < 81920) { v = wl3[i - 49152]; u = wr3[i - 49152]; }
    else                { v = wl4[i - 81920]; u = wr4[i - 81920]; }
    WL[i] = f2b(v);
    WR[i] = f2b(u);
  }
}

// ---------------- stage 128 rows (chain0 only): raw bf16 + rms scale ----------------
__device__ inline void stage_flows128(const float* __restrict__ flows, int blk,
                                      char* Xt, float* sArr, int wv, int lane) {
  for (int r = 0; r < 32; ++r) {
    int row = wv * 32 + r;
    const float2 v = *reinterpret_cast<const float2*>(
        flows + ((size_t)blk * 128 + row) * 128 + lane * 2);
    float ss = v.x * v.x + v.y * v.y;
    ss += __shfl_xor(ss, 32); ss += __shfl_xor(ss, 16); ss += __shfl_xor(ss, 8);
    ss += __shfl_xor(ss, 4);  ss += __shfl_xor(ss, 2);  ss += __shfl_xor(ss, 1);
    unsigned pk = (unsigned)f2b(v.x) | ((unsigned)f2b(v.y) << 16);
    *reinterpret_cast<unsigned*>(Xt + row * 256 + ((lane * 4) ^ ((row & 7) << 4))) = pk;
    if (lane == 0) sArr[row] = rsqrtf(ss * (1.0f / 128.0f));
  }
}

// ---------------- stage 64 rows (sage_fused): 8 unrolled float4 loads per wave ----------------
__device__ inline void stage_flows64(const float* __restrict__ flows, int blk,
                                     char* Xt, float* sArr, int wv, int lane) {
  int r2 = lane >> 5;            // which of the 2 rows this lane covers
  int c4 = lane & 31;            // float4 index within row
  #pragma unroll
  for (int it = 0; it < 8; ++it) {
    int rowbase = wv * 16 + it * 2;
    const float4 v = *reinterpret_cast<const float4*>(
        flows + ((size_t)blk * 64 + rowbase) * 128 + lane * 4);
    int row = rowbase + r2;
    float ss = v.x * v.x + v.y * v.y + v.z * v.z + v.w * v.w;
    ss += __shfl_xor(ss, 16); ss += __shfl_xor(ss, 8);
    ss += __shfl_xor(ss, 4);  ss += __shfl_xor(ss, 2); ss += __shfl_xor(ss, 1);
    uint2 pk;
    pk.x = (unsigned)f2b(v.x) | ((unsigned)f2b(v.y) << 16);
    pk.y = (unsigned)f2b(v.z) | ((unsigned)f2b(v.w) << 16);
    *reinterpret_cast<uint2*>(Xt + row * 256 + ((c4 * 8) ^ ((row & 7) << 4))) = pk;
    if (c4 == 0) sArr[row] = rsqrtf(ss * (1.0f / 128.0f));
  }
}

// ---------------- mid SAGE layer (64-row block): y = s.x@Wr^T + b (+corr) ----------------
template <int K, int N>
__device__ inline void sage_layer_mid64(char* Xt, const float* sP, float* sN,
                                        const ushort* __restrict__ Wr,
                                        const float* __restrict__ bias,
                                        const float* __restrict__ corr, bool useCorr,
                                        int wv, int lr, int lg) {
  __syncthreads();
  bf16x8 a[K / 32];
  float sr[4];
  int rowA = wv * 16 + lr;
  #pragma unroll
  for (int ks = 0; ks < K / 32; ++ks)
    a[ks] = *reinterpret_cast<const bf16x8*>(
        Xt + rowA * (K * 2) + ((ks * 64 + lg * 16) ^ ((rowA & 7) << 4)));
  #pragma unroll
  for (int rr = 0; rr < 4; ++rr) sr[rr] = sP[wv * 16 + 4 * lg + rr];
  __syncthreads();
  float ssq[4] = {0.f, 0.f, 0.f, 0.f};
  #pragma unroll
  for (int nt = 0; nt < N / 16; ++nt) {
    int col = nt * 16 + lr;
    bf16x8 b[K / 32];
    #pragma unroll
    for (int ks = 0; ks < K / 32; ++ks)
      b[ks] = *reinterpret_cast<const bf16x8*>(Wr + col * K + ks * 32 + lg * 8);
    f32x4 acc = {0.f, 0.f, 0.f, 0.f};
    #pragma unroll
    for (int ks = 0; ks < K / 32; ++ks)
      acc = __builtin_amdgcn_mfma_f32_16x16x32_bf16(a[ks], b[ks], acc, 0, 0, 0);
    float bb = bias[col];
    #pragma unroll
    for (int rr = 0; rr < 4; ++rr) {
      int row = wv * 16 + 4 * lg + rr;
      float y = acc[rr] * sr[rr] + bb;
      if (useCorr) y += corr[row * N + col];
      *reinterpret_cast<ushort*>(Xt + row * (N * 2) + ((col * 2) ^ ((row & 7) << 4))) = f2b(y);
      ssq[rr] += y * y;
    }
  }
  #pragma unroll
  for (int rr = 0; rr < 4; ++rr) {
    float ss = ssq[rr];
    ss += __shfl_xor(ss, 1); ss += __shfl_xor(ss, 2);
    ss += __shfl_xor(ss, 4); ss += __shfl_xor(ss, 8);
    if (lr == 0) sN[wv * 16 + 4 * lg + rr] = 1.0f / fmaxf(sqrtf(ss), 1e-12f);
  }
}

// ---------------- last SAGE layer (64-row block): L2 -> relu -> rms -> F ----------------
__device__ inline void sage_layer_last64(char* Xt, const float* sP,
                                         const ushort* __restrict__ Wr,
                                         const float* __restrict__ bias,
                                         const float* __restrict__ corr, bool useCorr,
                                         int wv, int lr, int lg,
                                         ushort* __restrict__ Fg, int blk) {
  __syncthreads();
  bf16x8 a[4];
  float sr[4];
  int rowA = wv * 16 + lr;
  #pragma unroll
  for (int ks = 0; ks < 4; ++ks)
    a[ks] = *reinterpret_cast<const bf16x8*>(
        Xt + rowA * 256 + ((ks * 64 + lg * 16) ^ ((rowA & 7) << 4)));
  #pragma unroll
  for (int rr = 0; rr < 4; ++rr) sr[rr] = sP[wv * 16 + 4 * lg + rr];
  __syncthreads();
  float yreg[8][4];
  float ssq[4] = {0.f, 0.f, 0.f, 0.f};
  #pragma unroll
  for (int nt = 0; nt < 8; ++nt) {
    int col = nt * 16 + lr;
    bf16x8 b[4];
    #pragma unroll
    for (int ks = 0; ks < 4; ++ks)
      b[ks] = *reinterpret_cast<const bf16x8*>(Wr + col * 128 + ks * 32 + lg * 8);
    f32x4 acc = {0.f, 0.f, 0.f, 0.f};
    #pragma unroll
    for (int ks = 0; ks < 4; ++ks)
      acc = __builtin_amdgcn_mfma_f32_16x16x32_bf16(a[ks], b[ks], acc, 0, 0, 0);
    float bb = bias[col];
    #pragma unroll
    for (int rr = 0; rr < 4; ++rr) {
      int row = wv * 16 + 4 * lg + rr;
      float y = acc[rr] * sr[rr] + bb;
      if (useCorr) y += corr[row * 128 + col];
      yreg[nt][rr] = y;
      ssq[rr] += y * y;
    }
  }
  float inv[4], sc[4];
  #pragma unroll
  for (int rr = 0; rr < 4; ++rr) {
    float ss = ssq[rr];
    ss += __shfl_xor(ss, 1); ss += __shfl_xor(ss, 2);
    ss += __shfl_xor(ss, 4); ss += __shfl_xor(ss, 8);
    inv[rr] = 1.0f / fmaxf(sqrtf(ss), 1e-12f);
  }
  float ss2[4] = {0.f, 0.f, 0.f, 0.f};
  #pragma unroll
  for (int nt = 0; nt < 8; ++nt)
    #pragma unroll
    for (int rr = 0; rr < 4; ++rr) {
      float v = fmaxf(yreg[nt][rr] * inv[rr], 0.f);
      yreg[nt][rr] = v;
      ss2[rr] += v * v;
    }
  #pragma unroll
  for (int rr = 0; rr < 4; ++rr) {
    float ss = ss2[rr];
    ss += __shfl_xor(ss, 1); ss += __shfl_xor(ss, 2);
    ss += __shfl_xor(ss, 4); ss += __shfl_xor(ss, 8);
    sc[rr] = sqrtf(128.0f / fmaxf(ss, 1e-20f));
  }
  #pragma unroll
  for (int nt = 0; nt < 8; ++nt)
    #pragma unroll
    for (int rr = 0; rr < 4; ++rr) {
      int row = wv * 16 + 4 * lg + rr;
      Fg[((size_t)blk * 64 + row) * 128 + nt * 16 + lr] = f2b(yreg[nt][rr] * sc[rr]);
    }
}

// ---------------- K2: fused SAGE, 512 blocks x 64 rows ----------------
__global__ __launch_bounds__(256, 2) void sage_fused(
    const float* __restrict__ flows, const ushort* __restrict__ WR,
    const float* __restrict__ bl1, const float* __restrict__ bl2,
    const float* __restrict__ bl3, const float* __restrict__ bl4,
    const float* __restrict__ C1, const float* __restrict__ C2,
    const float* __restrict__ C3, const float* __restrict__ C4,
    ushort* __restrict__ Fg) {
  __shared__ char Xt[32768];
  __shared__ float sA[64], sB[64];
  int blk = blockIdx.x, tid = threadIdx.x;
  int lane = tid & 63, wv = tid >> 6, lr = lane & 15, lg = lane >> 4;
  stage_flows64(flows, blk, Xt, sA, wv, lane);
  bool c = (blk < 2);
  int ro = c ? blk * 64 : 0;
  sage_layer_mid64<128, 128>(Xt, sA, sB, WR + 0,     bl1, C1 + ro * 128, c, wv, lr, lg);
  sage_layer_mid64<128, 256>(Xt, sB, sA, WR + 16384, bl2, C2 + ro * 256, c, wv, lr, lg);
  sage_layer_mid64<256, 128>(Xt, sA, sB, WR + 49152, bl3, C3 + ro * 128, c, wv, lr, lg);
  sage_layer_last64(Xt, sB, WR + 81920, bl4, C4 + ro * 128, c, wv, lr, lg, Fg, blk);
}

// ---------------- K1: batch-0 chain -> corr tables (128 rows, 1 block) ----------------
template <int K, int N, bool CORRONLY>
__device__ inline void chain_layer(char* Xt, char* C0T, const float* sP, float* sN,
                                   const ushort* __restrict__ Wl, const ushort* __restrict__ Wr,
                                   const float* __restrict__ bias, float* __restrict__ Cg,
                                   int wv, int lr, int lg) {
  __syncthreads();
  bf16x8 a[2][K / 32];
  float sr[2][4];
  #pragma unroll
  for (int m = 0; m < 2; ++m) {
    int rowA = wv * 32 + m * 16 + lr;
    #pragma unroll
    for (int ks = 0; ks < K / 32; ++ks)
      a[m][ks] = *reinterpret_cast<const bf16x8*>(
          Xt + rowA * (K * 2) + ((ks * 64 + lg * 16) ^ ((rowA & 7) << 4)));
    #pragma unroll
    for (int rr = 0; rr < 4; ++rr) sr[m][rr] = sP[wv * 32 + m * 16 + 4 * lg + rr];
  }
  __syncthreads();
  // pass 1: C0 = s.X @ Wl^T -> C0T[col][row] bf16 (transposed, swizzled)
  #pragma unroll
  for (int nt = 0; nt < N / 16; ++nt) {
    int col = nt * 16 + lr;
    bf16x8 b[K / 32];
    #pragma unroll
    for (int ks = 0; ks < K / 32; ++ks)
      b[ks] = *reinterpret_cast<const bf16x8*>(Wl + col * K + ks * 32 + lg * 8);
    f32x4 acc[2] = {{0.f, 0.f, 0.f, 0.f}, {0.f, 0.f, 0.f, 0.f}};
    #pragma unroll
    for (int ks = 0; ks < K / 32; ++ks) {
      acc[0] = __builtin_amdgcn_mfma_f32_16x16x32_bf16(a[0][ks], b[ks], acc[0], 0, 0, 0);
      acc[1] = __builtin_amdgcn_mfma_f32_16x16x32_bf16(a[1][ks], b[ks], acc[1], 0, 0, 0);
    }
    #pragma unroll
    for (int m = 0; m < 2; ++m)
      #pragma unroll
      for (int rr = 0; rr < 4; ++rr) {
        int row = wv * 32 + m * 16 + 4 * lg + rr;
        *reinterpret_cast<ushort*>(C0T + col * 256 + ((row * 2) ^ ((col & 7) << 4))) =
            f2b(acc[m][rr] * sr[m][rr]);
      }
  }
  __syncthreads();
  // build L A-fragments
  bf16x8 aL[2][4];
  #pragma unroll
  for (int m = 0; m < 2; ++m) {
    int rowL = wv * 32 + m * 16 + lr;
    ushort iv = f2b(1.0f / (float)(rowL > 1 ? rowL : 1));
    #pragma unroll
    for (int ks = 0; ks < 4; ++ks)
      #pragma unroll
      for (int j = 0; j < 8; ++j) {
        int k = ks * 32 + lg * 8 + j;
        aL[m][ks][j] = (short)((k < rowL) ? iv : 0);
      }
  }
  // pass 2: CORR = L @ C0 (write global); y = s.X @ Wr^T + b + CORR -> Xt
  float ssq[2][4] = {{0.f, 0.f, 0.f, 0.f}, {0.f, 0.f, 0.f, 0.f}};
  #pragma unroll
  for (int nt = 0; nt < N / 16; ++nt) {
    int col = nt * 16 + lr;
    bf16x8 bc[4];
    #pragma unroll
    for (int ks = 0; ks < 4; ++ks)
      bc[ks] = *reinterpret_cast<const bf16x8*>(
          C0T + col * 256 + ((ks * 64 + lg * 16) ^ ((col & 7) << 4)));
    f32x4 cacc[2] = {{0.f, 0.f, 0.f, 0.f}, {0.f, 0.f, 0.f, 0.f}};
    #pragma unroll
    for (int ks = 0; ks < 4; ++ks) {
      cacc[0] = __builtin_amdgcn_mfma_f32_16x16x32_bf16(aL[0][ks], bc[ks], cacc[0], 0, 0, 0);
      cacc[1] = __builtin_amdgcn_mfma_f32_16x16x32_bf16(aL[1][ks], bc[ks], cacc[1], 0, 0, 0);
    }
    #pragma unroll
    for (int m = 0; m < 2; ++m)
      #pragma unroll
      for (int rr = 0; rr < 4; ++rr) {
        int row = wv * 32 + m * 16 + 4 * lg + rr;
        Cg[row * N + col] = cacc[m][rr];
      }
    if (!CORRONLY) {
      bf16x8 b[K / 32];
      #pragma unroll
      for (int ks = 0; ks < K / 32; ++ks)
        b[ks] = *reinterpret_cast<const bf16x8*>(Wr + col * K + ks * 32 + lg * 8);
      f32x4 acc[2] = {{0.f, 0.f, 0.f, 0.f}, {0.f, 0.f, 0.f, 0.f}};
      #pragma unroll
      for (int ks = 0; ks < K / 32; ++ks) {
        acc[0] = __builtin_amdgcn_mfma_f32_16x16x32_bf16(a[0][ks], b[ks], acc[0], 0, 0, 0);
        acc[1] = __builtin_amdgcn_mfma_f32_16x16x32_bf16(a[1][ks], b[ks], acc[1], 0, 0, 0);
      }
      float bb = bias[col];
      #pragma unroll
      for (int m = 0; m < 2; ++m)
        #pragma unroll
        for (int rr = 0; rr < 4; ++rr) {
          int row = wv * 32 + m * 16 + 4 * lg + rr;
          float y = acc[m][rr] * sr[m][rr] + bb + cacc[m][rr];
          *reinterpret_cast<ushort*>(Xt + row * (N * 2) + ((col * 2) ^ ((row & 7) << 4))) = f2b(y);
          ssq[m][rr] += y * y;
        }
    }
  }
  if (!CORRONLY) {
    #pragma unroll
    for (int m = 0; m < 2; ++m)
      #pragma unroll
      for (int rr = 0; rr < 4; ++rr) {
        float ss = ssq[m][rr];
        ss += __shfl_xor(ss, 1); ss += __shfl_xor(ss, 2);
        ss += __shfl_xor(ss, 4); ss += __shfl_xor(ss, 8);
        if (lr == 0) sN[wv * 32 + m * 16 + 4 * lg + rr] = 1.0f / fmaxf(sqrtf(ss), 1e-12f);
      }
  }
}

__global__ __launch_bounds__(256, 1) void chain0_k(
    const float* __restrict__ flows, const ushort* __restrict__ WL, const ushort* __restrict__ WR,
    const float* __restrict__ bl1, const float* __restrict__ bl2, const float* __restrict__ bl3,
    float* __restrict__ C1, float* __restrict__ C2, float* __restrict__ C3, float* __restrict__ C4) {
  __shared__ char Xt[65536];
  __shared__ char C0T[65536];
  __shared__ float sA[128], sB[128];
  int tid = threadIdx.x;
  int lane = tid & 63, wv = tid >> 6, lr = lane & 15, lg = lane >> 4;
  stage_flows128(flows, 0, Xt, sA, wv, lane);
  chain_layer<128, 128, false>(Xt, C0T, sA, sB, WL + 0,     WR + 0,     bl1, C1, wv, lr, lg);
  chain_layer<128, 256, false>(Xt, C0T, sB, sA, WL + 16384, WR + 16384, bl2, C2, wv, lr, lg);
  chain_layer<256, 128, false>(Xt, C0T, sA, sB, WL + 49152, WR + 49152, bl3, C3, wv, lr, lg);
  chain_layer<128, 128, true >(Xt, C0T, sB, sA, WL + 81920, WR + 81920, nullptr, C4, wv, lr, lg);
}

// ---------------- fused attention: one block per batch (unchanged, verified) ----------------
__global__ __launch_bounds__(256, 1) void attn_fused(
    const ushort* __restrict__ F, const ushort* __restrict__ QB,
    const ushort* __restrict__ KBf, const ushort* __restrict__ SB,
    float* __restrict__ Out) {
  __shared__ char lds[98304];
  char* Qlds = lds;
  char* KT   = lds + 32768;
  char* Tl   = lds + 65536;

  const int b = blockIdx.x;
  const int tid = threadIdx.x;
  const int l = tid & 63, wv = tid >> 6;
  const int wr = wv >> 1, wc = wv & 1;
  const int lr = l & 15, lg = l >> 4;

  const ushort* Fb = F + (size_t)b * 16384;

  bf16x8 ff[4][4];
  #pragma unroll
  for (int i = 0; i < 4; ++i) {
    int n = (wr * 4 + i) * 16 + lr;
    #pragma unroll
    for (int ks = 0; ks < 4; ++ks)
      ff[i][ks] = *reinterpret_cast<const bf16x8*>(Fb + n * 128 + ks * 32 + lg * 8);
  }

  f32x4 oacc[4][4];
  #pragma unroll
  for (int i = 0; i < 4; ++i)
    #pragma unroll
    for (int j = 0; j < 4; ++j) oacc[i][j] = f32x4{0.f, 0.f, 0.f, 0.f};

  for (int w = 0; w < 8; ++w) {
    const ushort* qw = QB  + w * 16384;
    const ushort* kw = KBf + w * 16384;
    const ushort* sw = SB  + w * 16384;

    #pragma unroll
    for (int j = 0; j < 4; ++j) {
      int o = (wc * 4 + j) * 16 + lr;
      bf16x8 bq[4], bk[4];
      #pragma unroll
      for (int ks = 0; ks < 4; ++ks) {
        bq[ks] = *reinterpret_cast<const bf16x8*>(qw + o * 128 + ks * 32 + lg * 8);
        bk[ks] = *reinterpret_cast<const bf16x8*>(kw + o * 128 + ks * 32 + lg * 8);
      }
      #pragma unroll
      for (int i = 0; i < 4; ++i) {
        f32x4 qa = {0.f, 0.f, 0.f, 0.f}, ka = {0.f, 0.f, 0.f, 0.f};
        #pragma unroll
        for (int ks = 0; ks < 4; ++ks) {
          qa = __builtin_amdgcn_mfma_f32_16x16x32_bf16(ff[i][ks], bq[ks], qa, 0, 0, 0);
          ka = __builtin_amdgcn_mfma_f32_16x16x32_bf16(ff[i][ks], bk[ks], ka, 0, 0, 0);
        }
        int nb = (wr * 4 + i) * 16 + lg * 4;
        #pragma unroll
        for (int r = 0; r < 4; ++r) {
          int n = nb + r;
          *reinterpret_cast<ushort*>(Qlds + n * 256 + ((o * 2) ^ ((n & 7) << 4))) = f2b(qa[r]);
        }
        uint2 pk;
        pk.x = (unsigned)f2b(ka[0]) | ((unsigned)f2b(ka[1]) << 16);
        pk.y = (unsigned)f2b(ka[2]) | ((unsigned)f2b(ka[3]) << 16);
        int m2 = ((wr * 4 + i) * 16 + lg * 4) * 2;
        *reinterpret_cast<uint2*>(KT + o * 256 + (m2 ^ ((o & 7) << 4))) = pk;
      }
    }
    __syncthreads();

    bf16x8 as[4][4];
    #pragma unroll
    for (int i = 0; i < 4; ++i) {
      int p = (wr * 4 + i) * 16 + lr;
      #pragma unroll
      for (int ks = 0; ks < 4; ++ks)
        as[i][ks] = *reinterpret_cast<const bf16x8*>(sw + p * 128 + ks * 32 + lg * 8);
    }
    #pragma unroll
    for (int j = 0; j < 4; ++j) {
      int o = (wc * 4 + j) * 16 + lr;
      bf16x8 bkt[4];
      #pragma unroll
      for (int ks = 0; ks < 4; ++ks)
        bkt[ks] = *reinterpret_cast<const bf16x8*>(KT + o * 256 + ((ks * 64 + lg * 16) ^ ((o & 7) << 4)));
      #pragma unroll
      for (int i = 0; i < 4; ++i) {
        f32x4 ta = {0.f, 0.f, 0.f, 0.f};
        #pragma unroll
        for (int ks = 0; ks < 4; ++ks)
          ta = __builtin_amdgcn_mfma_f32_16x16x32_bf16(as[i][ks], bkt[ks], ta, 0, 0, 0);
        int pb = (wr * 4 + i) * 16 + lg * 4;
        #pragma unroll
        for (int r = 0; r < 4; ++r) {
          int p = pb + r;
          *reinterpret_cast<ushort*>(Tl + p * 256 + ((o * 2) ^ ((p & 7) << 4))) = f2b(ta[r]);
        }
      }
    }
    __syncthreads();

    bf16x8 aq[4][4];
    #pragma unroll
    for (int i = 0; i < 4; ++i) {
      int n = (wr * 4 + i) * 16 + lr;
      #pragma unroll
      for (int ks = 0; ks < 4; ++ks)
        aq[i][ks] = *reinterpret_cast<const bf16x8*>(Qlds + n * 256 + ((ks * 64 + lg * 16) ^ ((n & 7) << 4)));
    }
    #pragma unroll
    for (int j = 0; j < 4; ++j) {
      int p = (wc * 4 + j) * 16 + lr;
      bf16x8 bt[4];
      #pragma unroll
      for (int ks = 0; ks < 4; ++ks)
        bt[ks] = *reinterpret_cast<const bf16x8*>(Tl + p * 256 + ((ks * 64 + lg * 16) ^ ((p & 7) << 4)));
      #pragma unroll
      for (int i = 0; i < 4; ++i)
        #pragma unroll
        for (int ks = 0; ks < 4; ++ks)
          oacc[i][j] = __builtin_amdgcn_mfma_f32_16x16x32_bf16(aq[i][ks], bt[ks], oacc[i][j], 0, 0, 0);
    }
    __syncthreads();
  }

  const float inv_scale = 0.08838834764831845f;
  float* ob = Out + (size_t)b * 16384;
  #pragma unroll
  for (int i = 0; i < 4; ++i) {
    int nb = (wr * 4 + i) * 16 + lg * 4;
    #pragma unroll
    for (int j = 0; j < 4; ++j) {
      int p = (wc * 4 + j) * 16 + lr;
      #pragma unroll
      for (int r = 0; r < 4; ++r)
        ob[(nb + r) * 128 + p] = oacc[i][j][r] * inv_scale;
    }
  }
}

extern "C" void kernel_launch(void* const* d_in, const int* in_sizes, int n_in,
                              void* d_out, int out_size, void* d_ws, size_t ws_size,
                              hipStream_t stream) {
  const float* flows = (const float*)d_in[0];
  const float* g1_wl = (const float*)d_in[10];
  const float* g1_bl = (const float*)d_in[11];
  const float* g1_wr = (const float*)d_in[12];
  const float* g2_wl = (const float*)d_in[13];
  const float* g2_bl = (const float*)d_in[14];
  const float* g2_wr = (const float*)d_in[15];
  const float* g3_wl = (const float*)d_in[16];
  const float* g3_bl = (const float*)d_in[17];
  const float* g3_wr = (const float*)d_in[18];
  const float* g4_wl = (const float*)d_in[19];
  const float* g4_bl = (const float*)d_in[20];
  const float* g4_wr = (const float*)d_in[21];
  const float* qsa   = (const float*)d_in[24];
  const float* ksa   = (const float*)d_in[25];
  const float* s2w   = (const float*)d_in[27];
  float* out = (float*)d_out;
  char* wsb  = (char*)d_ws;

  // workspace layout (bytes)
  ushort* FB16 = (ushort*)(wsb);                 // 32768*128 bf16 = 8388608
  ushort* QB   = (ushort*)(wsb + 8388608);       // 131072 bf16
  ushort* KB2  = (ushort*)(wsb + 8650752);
  ushort* SB   = (ushort*)(wsb + 8912896);
  ushort* WL   = (ushort*)(wsb + 9175040);       // 98304 bf16
  ushort* WR   = (ushort*)(wsb + 9371648);
  float*  C1   = (float*)(wsb + 9568256);        // 128*128 f32
  float*  C2   = (float*)(wsb + 9633792);        // 128*256 f32
  float*  C3   = (float*)(wsb + 9764864);        // 128*128 f32
  float*  C4   = (float*)(wsb + 9830400);        // 128*128 f32

  prep_all_k<<<896, 256, 0, stream>>>(qsa, ksa, s2w,
                                      g1_wl, g2_wl, g3_wl, g4_wl,
                                      g1_wr, g2_wr, g3_wr, g4_wr,
                                      QB, KB2, SB, WL, WR);
  chain0_k<<<1, 256, 0, stream>>>(flows, WL, WR, g1_bl, g2_bl, g3_bl, C1, C2, C3, C4);
  sage_fused<<<512, 256, 0, stream>>>(flows, WR, g1_bl, g2_bl, g3_bl, g4_bl,
                                      C1, C2, C3, C4, FB16);
  attn_fused<<<256, 256, 0, stream>>>(FB16, QB, KB2, SB, out);
}

// Round 9
// 277.094 us; speedup vs baseline: 7.5450x; 1.0726x over previous
//
#include <hip/hip_runtime.h>
#include <math.h>

// Model_6150393168181 — fully bf16-MFMA pipeline.
// out[b] = (1/sqrt(128)) * sum_w (f qsa_w^T) (S_w f ksa_w^T)^T
// f = rms(relu(SAGE4(rms(flows)))); SAGE agg = exclusive-prefix-mean over batch-0 rows,
// corr_l = L @ (X_l @ wl_l^T), L[n][i] = (i<n)/max(n,1)  (MFMA-able, chain0_k).
// attn_fused: 512 threads (8 waves, 2x4 wave grid) for 2 waves/SIMD latency hiding.

typedef __attribute__((ext_vector_type(8))) short bf16x8;
typedef __attribute__((ext_vector_type(4))) float f32x4;

__device__ inline ushort f2b(float x) {
  unsigned u = __builtin_bit_cast(unsigned, x);
  unsigned r = (u + 0x7fffu + ((u >> 16) & 1u)) >> 16;
  return (ushort)r;
}

// ---------------- prep: all bf16 weight conversions ----------------
__global__ __launch_bounds__(256) void prep_all_k(
    const float* __restrict__ qsa, const float* __restrict__ ksa, const float* __restrict__ s2w,
    const float* __restrict__ wl1, const float* __restrict__ wl2,
    const float* __restrict__ wl3, const float* __restrict__ wl4,
    const float* __restrict__ wr1, const float* __restrict__ wr2,
    const float* __restrict__ wr3, const float* __restrict__ wr4,
    ushort* __restrict__ QB, ushort* __restrict__ KB2, ushort* __restrict__ SB,
    ushort* __restrict__ WL, ushort* __restrict__ WR) {
  int i = blockIdx.x * 256 + threadIdx.x;
  if (i < 131072) {
    QB[i] = f2b(qsa[i]);
    KB2[i] = f2b(ksa[i]);
    int w = i >> 14, p = (i >> 7) & 127, m = i & 127;
    SB[i] = f2b(s2w[p * 1024 + m * 8 + w]);
    return;
  }
  i -= 131072;
  if (i < 98304) {
    float v, u;
    if      (i < 16384) { v = wl1[i];         u = wr1[i]; }
    else if (i < 49152) { v = wl2[i - 16384]; u = wr2[i - 16384]; }
    else if (i < 81920) { v = wl3[i - 49152]; u = wr3[i - 49152]; }
    else                { v = wl4[i - 81920]; u = wr4[i - 81920]; }
    WL[i] = f2b(v);
    WR[i] = f2b(u);
  }
}

// ---------------- stage 128 rows (chain0 only): raw bf16 + rms scale ----------------
__device__ inline void stage_flows128(const float* __restrict__ flows, int blk,
                                      char* Xt, float* sArr, int wv, int lane) {
  for (int r = 0; r < 32; ++r) {
    int row = wv * 32 + r;
    const float2 v = *reinterpret_cast<const float2*>(
        flows + ((size_t)blk * 128 + row) * 128 + lane * 2);
    float ss = v.x * v.x + v.y * v.y;
    ss += __shfl_xor(ss, 32); ss += __shfl_xor(ss, 16); ss += __shfl_xor(ss, 8);
    ss += __shfl_xor(ss, 4);  ss += __shfl_xor(ss, 2);  ss += __shfl_xor(ss, 1);
    unsigned pk = (unsigned)f2b(v.x) | ((unsigned)f2b(v.y) << 16);
    *reinterpret_cast<unsigned*>(Xt + row * 256 + ((lane * 4) ^ ((row & 7) << 4))) = pk;
    if (lane == 0) sArr[row] = rsqrtf(ss * (1.0f / 128.0f));
  }
}

// ---------------- stage 64 rows (sage_fused): 8 unrolled float4 loads per wave ----------------
__device__ inline void stage_flows64(const float* __restrict__ flows, int blk,
                                     char* Xt, float* sArr, int wv, int lane) {
  int r2 = lane >> 5;            // which of the 2 rows this lane covers
  int c4 = lane & 31;            // float4 index within row
  #pragma unroll
  for (int it = 0; it < 8; ++it) {
    int rowbase = wv * 16 + it * 2;
    const float4 v = *reinterpret_cast<const float4*>(
        flows + ((size_t)blk * 64 + rowbase) * 128 + lane * 4);
    int row = rowbase + r2;
    float ss = v.x * v.x + v.y * v.y + v.z * v.z + v.w * v.w;
    ss += __shfl_xor(ss, 16); ss += __shfl_xor(ss, 8);
    ss += __shfl_xor(ss, 4);  ss += __shfl_xor(ss, 2); ss += __shfl_xor(ss, 1);
    uint2 pk;
    pk.x = (unsigned)f2b(v.x) | ((unsigned)f2b(v.y) << 16);
    pk.y = (unsigned)f2b(v.z) | ((unsigned)f2b(v.w) << 16);
    *reinterpret_cast<uint2*>(Xt + row * 256 + ((c4 * 8) ^ ((row & 7) << 4))) = pk;
    if (c4 == 0) sArr[row] = rsqrtf(ss * (1.0f / 128.0f));
  }
}

// ---------------- mid SAGE layer (64-row block): y = s.x@Wr^T + b (+corr) ----------------
template <int K, int N>
__device__ inline void sage_layer_mid64(char* Xt, const float* sP, float* sN,
                                        const ushort* __restrict__ Wr,
                                        const float* __restrict__ bias,
                                        const float* __restrict__ corr, bool useCorr,
                                        int wv, int lr, int lg) {
  __syncthreads();
  bf16x8 a[K / 32];
  float sr[4];
  int rowA = wv * 16 + lr;
  #pragma unroll
  for (int ks = 0; ks < K / 32; ++ks)
    a[ks] = *reinterpret_cast<const bf16x8*>(
        Xt + rowA * (K * 2) + ((ks * 64 + lg * 16) ^ ((rowA & 7) << 4)));
  #pragma unroll
  for (int rr = 0; rr < 4; ++rr) sr[rr] = sP[wv * 16 + 4 * lg + rr];
  __syncthreads();
  float ssq[4] = {0.f, 0.f, 0.f, 0.f};
  #pragma unroll
  for (int nt = 0; nt < N / 16; ++nt) {
    int col = nt * 16 + lr;
    bf16x8 b[K / 32];
    #pragma unroll
    for (int ks = 0; ks < K / 32; ++ks)
      b[ks] = *reinterpret_cast<const bf16x8*>(Wr + col * K + ks * 32 + lg * 8);
    f32x4 acc = {0.f, 0.f, 0.f, 0.f};
    #pragma unroll
    for (int ks = 0; ks < K / 32; ++ks)
      acc = __builtin_amdgcn_mfma_f32_16x16x32_bf16(a[ks], b[ks], acc, 0, 0, 0);
    float bb = bias[col];
    #pragma unroll
    for (int rr = 0; rr < 4; ++rr) {
      int row = wv * 16 + 4 * lg + rr;
      float y = acc[rr] * sr[rr] + bb;
      if (useCorr) y += corr[row * N + col];
      *reinterpret_cast<ushort*>(Xt + row * (N * 2) + ((col * 2) ^ ((row & 7) << 4))) = f2b(y);
      ssq[rr] += y * y;
    }
  }
  #pragma unroll
  for (int rr = 0; rr < 4; ++rr) {
    float ss = ssq[rr];
    ss += __shfl_xor(ss, 1); ss += __shfl_xor(ss, 2);
    ss += __shfl_xor(ss, 4); ss += __shfl_xor(ss, 8);
    if (lr == 0) sN[wv * 16 + 4 * lg + rr] = 1.0f / fmaxf(sqrtf(ss), 1e-12f);
  }
}

// ---------------- last SAGE layer (64-row block): L2 -> relu -> rms -> F ----------------
__device__ inline void sage_layer_last64(char* Xt, const float* sP,
                                         const ushort* __restrict__ Wr,
                                         const float* __restrict__ bias,
                                         const float* __restrict__ corr, bool useCorr,
                                         int wv, int lr, int lg,
                                         ushort* __restrict__ Fg, int blk) {
  __syncthreads();
  bf16x8 a[4];
  float sr[4];
  int rowA = wv * 16 + lr;
  #pragma unroll
  for (int ks = 0; ks < 4; ++ks)
    a[ks] = *reinterpret_cast<const bf16x8*>(
        Xt + rowA * 256 + ((ks * 64 + lg * 16) ^ ((rowA & 7) << 4)));
  #pragma unroll
  for (int rr = 0; rr < 4; ++rr) sr[rr] = sP[wv * 16 + 4 * lg + rr];
  __syncthreads();
  float yreg[8][4];
  float ssq[4] = {0.f, 0.f, 0.f, 0.f};
  #pragma unroll
  for (int nt = 0; nt < 8; ++nt) {
    int col = nt * 16 + lr;
    bf16x8 b[4];
    #pragma unroll
    for (int ks = 0; ks < 4; ++ks)
      b[ks] = *reinterpret_cast<const bf16x8*>(Wr + col * 128 + ks * 32 + lg * 8);
    f32x4 acc = {0.f, 0.f, 0.f, 0.f};
    #pragma unroll
    for (int ks = 0; ks < 4; ++ks)
      acc = __builtin_amdgcn_mfma_f32_16x16x32_bf16(a[ks], b[ks], acc, 0, 0, 0);
    float bb = bias[col];
    #pragma unroll
    for (int rr = 0; rr < 4; ++rr) {
      int row = wv * 16 + 4 * lg + rr;
      float y = acc[rr] * sr[rr] + bb;
      if (useCorr) y += corr[row * 128 + col];
      yreg[nt][rr] = y;
      ssq[rr] += y * y;
    }
  }
  float inv[4], sc[4];
  #pragma unroll
  for (int rr = 0; rr < 4; ++rr) {
    float ss = ssq[rr];
    ss += __shfl_xor(ss, 1); ss += __shfl_xor(ss, 2);
    ss += __shfl_xor(ss, 4); ss += __shfl_xor(ss, 8);
    inv[rr] = 1.0f / fmaxf(sqrtf(ss), 1e-12f);
  }
  float ss2[4] = {0.f, 0.f, 0.f, 0.f};
  #pragma unroll
  for (int nt = 0; nt < 8; ++nt)
    #pragma unroll
    for (int rr = 0; rr < 4; ++rr) {
      float v = fmaxf(yreg[nt][rr] * inv[rr], 0.f);
      yreg[nt][rr] = v;
      ss2[rr] += v * v;
    }
  #pragma unroll
  for (int rr = 0; rr < 4; ++rr) {
    float ss = ss2[rr];
    ss += __shfl_xor(ss, 1); ss += __shfl_xor(ss, 2);
    ss += __shfl_xor(ss, 4); ss += __shfl_xor(ss, 8);
    sc[rr] = sqrtf(128.0f / fmaxf(ss, 1e-20f));
  }
  #pragma unroll
  for (int nt = 0; nt < 8; ++nt)
    #pragma unroll
    for (int rr = 0; rr < 4; ++rr) {
      int row = wv * 16 + 4 * lg + rr;
      Fg[((size_t)blk * 64 + row) * 128 + nt * 16 + lr] = f2b(yreg[nt][rr] * sc[rr]);
    }
}

// ---------------- K2: fused SAGE, 512 blocks x 64 rows ----------------
__global__ __launch_bounds__(256, 2) void sage_fused(
    const float* __restrict__ flows, const ushort* __restrict__ WR,
    const float* __restrict__ bl1, const float* __restrict__ bl2,
    const float* __restrict__ bl3, const float* __restrict__ bl4,
    const float* __restrict__ C1, const float* __restrict__ C2,
    const float* __restrict__ C3, const float* __restrict__ C4,
    ushort* __restrict__ Fg) {
  __shared__ char Xt[32768];
  __shared__ float sA[64], sB[64];
  int blk = blockIdx.x, tid = threadIdx.x;
  int lane = tid & 63, wv = tid >> 6, lr = lane & 15, lg = lane >> 4;
  stage_flows64(flows, blk, Xt, sA, wv, lane);
  bool c = (blk < 2);
  int ro = c ? blk * 64 : 0;
  sage_layer_mid64<128, 128>(Xt, sA, sB, WR + 0,     bl1, C1 + ro * 128, c, wv, lr, lg);
  sage_layer_mid64<128, 256>(Xt, sB, sA, WR + 16384, bl2, C2 + ro * 256, c, wv, lr, lg);
  sage_layer_mid64<256, 128>(Xt, sA, sB, WR + 49152, bl3, C3 + ro * 128, c, wv, lr, lg);
  sage_layer_last64(Xt, sB, WR + 81920, bl4, C4 + ro * 128, c, wv, lr, lg, Fg, blk);
}

// ---------------- K1: batch-0 chain -> corr tables (128 rows, 1 block) ----------------
template <int K, int N, bool CORRONLY>
__device__ inline void chain_layer(char* Xt, char* C0T, const float* sP, float* sN,
                                   const ushort* __restrict__ Wl, const ushort* __restrict__ Wr,
                                   const float* __restrict__ bias, float* __restrict__ Cg,
                                   int wv, int lr, int lg) {
  __syncthreads();
  bf16x8 a[2][K / 32];
  float sr[2][4];
  #pragma unroll
  for (int m = 0; m < 2; ++m) {
    int rowA = wv * 32 + m * 16 + lr;
    #pragma unroll
    for (int ks = 0; ks < K / 32; ++ks)
      a[m][ks] = *reinterpret_cast<const bf16x8*>(
          Xt + rowA * (K * 2) + ((ks * 64 + lg * 16) ^ ((rowA & 7) << 4)));
    #pragma unroll
    for (int rr = 0; rr < 4; ++rr) sr[m][rr] = sP[wv * 32 + m * 16 + 4 * lg + rr];
  }
  __syncthreads();
  // pass 1: C0 = s.X @ Wl^T -> C0T[col][row] bf16 (transposed, swizzled)
  #pragma unroll
  for (int nt = 0; nt < N / 16; ++nt) {
    int col = nt * 16 + lr;
    bf16x8 b[K / 32];
    #pragma unroll
    for (int ks = 0; ks < K / 32; ++ks)
      b[ks] = *reinterpret_cast<const bf16x8*>(Wl + col * K + ks * 32 + lg * 8);
    f32x4 acc[2] = {{0.f, 0.f, 0.f, 0.f}, {0.f, 0.f, 0.f, 0.f}};
    #pragma unroll
    for (int ks = 0; ks < K / 32; ++ks) {
      acc[0] = __builtin_amdgcn_mfma_f32_16x16x32_bf16(a[0][ks], b[ks], acc[0], 0, 0, 0);
      acc[1] = __builtin_amdgcn_mfma_f32_16x16x32_bf16(a[1][ks], b[ks], acc[1], 0, 0, 0);
    }
    #pragma unroll
    for (int m = 0; m < 2; ++m)
      #pragma unroll
      for (int rr = 0; rr < 4; ++rr) {
        int row = wv * 32 + m * 16 + 4 * lg + rr;
        *reinterpret_cast<ushort*>(C0T + col * 256 + ((row * 2) ^ ((col & 7) << 4))) =
            f2b(acc[m][rr] * sr[m][rr]);
      }
  }
  __syncthreads();
  // build L A-fragments
  bf16x8 aL[2][4];
  #pragma unroll
  for (int m = 0; m < 2; ++m) {
    int rowL = wv * 32 + m * 16 + lr;
    ushort iv = f2b(1.0f / (float)(rowL > 1 ? rowL : 1));
    #pragma unroll
    for (int ks = 0; ks < 4; ++ks)
      #pragma unroll
      for (int j = 0; j < 8; ++j) {
        int k = ks * 32 + lg * 8 + j;
        aL[m][ks][j] = (short)((k < rowL) ? iv : 0);
      }
  }
  // pass 2: CORR = L @ C0 (write global); y = s.X @ Wr^T + b + CORR -> Xt
  float ssq[2][4] = {{0.f, 0.f, 0.f, 0.f}, {0.f, 0.f, 0.f, 0.f}};
  #pragma unroll
  for (int nt = 0; nt < N / 16; ++nt) {
    int col = nt * 16 + lr;
    bf16x8 bc[4];
    #pragma unroll
    for (int ks = 0; ks < 4; ++ks)
      bc[ks] = *reinterpret_cast<const bf16x8*>(
          C0T + col * 256 + ((ks * 64 + lg * 16) ^ ((col & 7) << 4)));
    f32x4 cacc[2] = {{0.f, 0.f, 0.f, 0.f}, {0.f, 0.f, 0.f, 0.f}};
    #pragma unroll
    for (int ks = 0; ks < 4; ++ks) {
      cacc[0] = __builtin_amdgcn_mfma_f32_16x16x32_bf16(aL[0][ks], bc[ks], cacc[0], 0, 0, 0);
      cacc[1] = __builtin_amdgcn_mfma_f32_16x16x32_bf16(aL[1][ks], bc[ks], cacc[1], 0, 0, 0);
    }
    #pragma unroll
    for (int m = 0; m < 2; ++m)
      #pragma unroll
      for (int rr = 0; rr < 4; ++rr) {
        int row = wv * 32 + m * 16 + 4 * lg + rr;
        Cg[row * N + col] = cacc[m][rr];
      }
    if (!CORRONLY) {
      bf16x8 b[K / 32];
      #pragma unroll
      for (int ks = 0; ks < K / 32; ++ks)
        b[ks] = *reinterpret_cast<const bf16x8*>(Wr + col * K + ks * 32 + lg * 8);
      f32x4 acc[2] = {{0.f, 0.f, 0.f, 0.f}, {0.f, 0.f, 0.f, 0.f}};
      #pragma unroll
      for (int ks = 0; ks < K / 32; ++ks) {
        acc[0] = __builtin_amdgcn_mfma_f32_16x16x32_bf16(a[0][ks], b[ks], acc[0], 0, 0, 0);
        acc[1] = __builtin_amdgcn_mfma_f32_16x16x32_bf16(a[1][ks], b[ks], acc[1], 0, 0, 0);
      }
      float bb = bias[col];
      #pragma unroll
      for (int m = 0; m < 2; ++m)
        #pragma unroll
        for (int rr = 0; rr < 4; ++rr) {
          int row = wv * 32 + m * 16 + 4 * lg + rr;
          float y = acc[m][rr] * sr[m][rr] + bb + cacc[m][rr];
          *reinterpret_cast<ushort*>(Xt + row * (N * 2) + ((col * 2) ^ ((row & 7) << 4))) = f2b(y);
          ssq[m][rr] += y * y;
        }
    }
  }
  if (!CORRONLY) {
    #pragma unroll
    for (int m = 0; m < 2; ++m)
      #pragma unroll
      for (int rr = 0; rr < 4; ++rr) {
        float ss = ssq[m][rr];
        ss += __shfl_xor(ss, 1); ss += __shfl_xor(ss, 2);
        ss += __shfl_xor(ss, 4); ss += __shfl_xor(ss, 8);
        if (lr == 0) sN[wv * 32 + m * 16 + 4 * lg + rr] = 1.0f / fmaxf(sqrtf(ss), 1e-12f);
      }
  }
}

__global__ __launch_bounds__(256, 1) void chain0_k(
    const float* __restrict__ flows, const ushort* __restrict__ WL, const ushort* __restrict__ WR,
    const float* __restrict__ bl1, const float* __restrict__ bl2, const float* __restrict__ bl3,
    float* __restrict__ C1, float* __restrict__ C2, float* __restrict__ C3, float* __restrict__ C4) {
  __shared__ char Xt[65536];
  __shared__ char C0T[65536];
  __shared__ float sA[128], sB[128];
  int tid = threadIdx.x;
  int lane = tid & 63, wv = tid >> 6, lr = lane & 15, lg = lane >> 4;
  stage_flows128(flows, 0, Xt, sA, wv, lane);
  chain_layer<128, 128, false>(Xt, C0T, sA, sB, WL + 0,     WR + 0,     bl1, C1, wv, lr, lg);
  chain_layer<128, 256, false>(Xt, C0T, sB, sA, WL + 16384, WR + 16384, bl2, C2, wv, lr, lg);
  chain_layer<256, 128, false>(Xt, C0T, sA, sB, WL + 49152, WR + 49152, bl3, C3, wv, lr, lg);
  chain_layer<128, 128, true >(Xt, C0T, sB, sA, WL + 81920, WR + 81920, nullptr, C4, wv, lr, lg);
}

// ---------------- fused attention: one block per batch, 8 waves (2x4) ----------------
// Wave (wr,wc): rows (wr*4+i)*16, i=0..3 (64 rows); cols o=(wc*2+j)*16+lr, j=0..1 (32 cols).
// Same MFMA order/count per output as the 4-wave version -> bit-identical results.
__global__ __launch_bounds__(512, 2) void attn_fused(
    const ushort* __restrict__ F, const ushort* __restrict__ QB,
    const ushort* __restrict__ KBf, const ushort* __restrict__ SB,
    float* __restrict__ Out) {
  __shared__ char lds[98304];
  char* Qlds = lds;
  char* KT   = lds + 32768;
  char* Tl   = lds + 65536;

  const int b = blockIdx.x;
  const int tid = threadIdx.x;
  const int l = tid & 63, wv = tid >> 6;
  const int wr = wv >> 2, wc = wv & 3;
  const int lr = l & 15, lg = l >> 4;

  const ushort* Fb = F + (size_t)b * 16384;

  bf16x8 ff[4][4];
  #pragma unroll
  for (int i = 0; i < 4; ++i) {
    int n = (wr * 4 + i) * 16 + lr;
    #pragma unroll
    for (int ks = 0; ks < 4; ++ks)
      ff[i][ks] = *reinterpret_cast<const bf16x8*>(Fb + n * 128 + ks * 32 + lg * 8);
  }

  f32x4 oacc[4][2];
  #pragma unroll
  for (int i = 0; i < 4; ++i)
    #pragma unroll
    for (int j = 0; j < 2; ++j) oacc[i][j] = f32x4{0.f, 0.f, 0.f, 0.f};

  for (int w = 0; w < 8; ++w) {
    const ushort* qw = QB  + w * 16384;
    const ushort* kw = KBf + w * 16384;
    const ushort* sw = SB  + w * 16384;

    // ---- G1 + G2: Q = f@qsa^T (->Qlds transposed), K = f@ksa^T (->KT transposed) ----
    #pragma unroll
    for (int j = 0; j < 2; ++j) {
      int o = (wc * 2 + j) * 16 + lr;
      bf16x8 bq[4], bk[4];
      #pragma unroll
      for (int ks = 0; ks < 4; ++ks) {
        bq[ks] = *reinterpret_cast<const bf16x8*>(qw + o * 128 + ks * 32 + lg * 8);
        bk[ks] = *reinterpret_cast<const bf16x8*>(kw + o * 128 + ks * 32 + lg * 8);
      }
      #pragma unroll
      for (int i = 0; i < 4; ++i) {
        f32x4 qa = {0.f, 0.f, 0.f, 0.f}, ka = {0.f, 0.f, 0.f, 0.f};
        #pragma unroll
        for (int ks = 0; ks < 4; ++ks) {
          qa = __builtin_amdgcn_mfma_f32_16x16x32_bf16(ff[i][ks], bq[ks], qa, 0, 0, 0);
          ka = __builtin_amdgcn_mfma_f32_16x16x32_bf16(ff[i][ks], bk[ks], ka, 0, 0, 0);
        }
        int nb = (wr * 4 + i) * 16 + lg * 4;
        #pragma unroll
        for (int r = 0; r < 4; ++r) {
          int n = nb + r;
          *reinterpret_cast<ushort*>(Qlds + n * 256 + ((o * 2) ^ ((n & 7) << 4))) = f2b(qa[r]);
        }
        uint2 pk;
        pk.x = (unsigned)f2b(ka[0]) | ((unsigned)f2b(ka[1]) << 16);
        pk.y = (unsigned)f2b(ka[2]) | ((unsigned)f2b(ka[3]) << 16);
        int m2 = ((wr * 4 + i) * 16 + lg * 4) * 2;
        *reinterpret_cast<uint2*>(KT + o * 256 + (m2 ^ ((o & 7) << 4))) = pk;
      }
    }
    __syncthreads();

    // ---- G3: T = S_w @ K ----
    bf16x8 as[4][4];
    #pragma unroll
    for (int i = 0; i < 4; ++i) {
      int p = (wr * 4 + i) * 16 + lr;
      #pragma unroll
      for (int ks = 0; ks < 4; ++ks)
        as[i][ks] = *reinterpret_cast<const bf16x8*>(sw + p * 128 + ks * 32 + lg * 8);
    }
    #pragma unroll
    for (int j = 0; j < 2; ++j) {
      int o = (wc * 2 + j) * 16 + lr;
      bf16x8 bkt[4];
      #pragma unroll
      for (int ks = 0; ks < 4; ++ks)
        bkt[ks] = *reinterpret_cast<const bf16x8*>(KT + o * 256 + ((ks * 64 + lg * 16) ^ ((o & 7) << 4)));
      #pragma unroll
      for (int i = 0; i < 4; ++i) {
        f32x4 ta = {0.f, 0.f, 0.f, 0.f};
        #pragma unroll
        for (int ks = 0; ks < 4; ++ks)
          ta = __builtin_amdgcn_mfma_f32_16x16x32_bf16(as[i][ks], bkt[ks], ta, 0, 0, 0);
        int pb = (wr * 4 + i) * 16 + lg * 4;
        #pragma unroll
        for (int r = 0; r < 4; ++r) {
          int p = pb + r;
          *reinterpret_cast<ushort*>(Tl + p * 256 + ((o * 2) ^ ((p & 7) << 4))) = f2b(ta[r]);
        }
      }
    }
    __syncthreads();

    // ---- G4: out += Q @ T^T ----
    bf16x8 aq[4][4];
    #pragma unroll
    for (int i = 0; i < 4; ++i) {
      int n = (wr * 4 + i) * 16 + lr;
      #pragma unroll
      for (int ks = 0; ks < 4; ++ks)
        aq[i][ks] = *reinterpret_cast<const bf16x8*>(Qlds + n * 256 + ((ks * 64 + lg * 16) ^ ((n & 7) << 4)));
    }
    #pragma unroll
    for (int j = 0; j < 2; ++j) {
      int p = (wc * 2 + j) * 16 + lr;
      bf16x8 bt[4];
      #pragma unroll
      for (int ks = 0; ks < 4; ++ks)
        bt[ks] = *reinterpret_cast<const bf16x8*>(Tl + p * 256 + ((ks * 64 + lg * 16) ^ ((p & 7) << 4)));
      #pragma unroll
      for (int i = 0; i < 4; ++i)
        #pragma unroll
        for (int ks = 0; ks < 4; ++ks)
          oacc[i][j] = __builtin_amdgcn_mfma_f32_16x16x32_bf16(aq[i][ks], bt[ks], oacc[i][j], 0, 0, 0);
    }
    __syncthreads();
  }

  const float inv_scale = 0.08838834764831845f;
  float* ob = Out + (size_t)b * 16384;
  #pragma unroll
  for (int i = 0; i < 4; ++i) {
    int nb = (wr * 4 + i) * 16 + lg * 4;
    #pragma unroll
    for (int j = 0; j < 2; ++j) {
      int p = (wc * 2 + j) * 16 + lr;
      #pragma unroll
      for (int r = 0; r < 4; ++r)
        ob[(nb + r) * 128 + p] = oacc[i][j][r] * inv_scale;
    }
  }
}

extern "C" void kernel_launch(void* const* d_in, const int* in_sizes, int n_in,
                              void* d_out, int out_size, void* d_ws, size_t ws_size,
                              hipStream_t stream) {
  const float* flows = (const float*)d_in[0];
  const float* g1_wl = (const float*)d_in[10];
  const float* g1_bl = (const float*)d_in[11];
  const float* g1_wr = (const float*)d_in[12];
  const float* g2_wl = (const float*)d_in[13];
  const float* g2_bl = (const float*)d_in[14];
  const float* g2_wr = (const float*)d_in[15];
  const float* g3_wl = (const float*)d_in[16];
  const float* g3_bl = (const float*)d_in[17];
  const float* g3_wr = (const float*)d_in[18];
  const float* g4_wl = (const float*)d_in[19];
  const float* g4_bl = (const float*)d_in[20];
  const float* g4_wr = (const float*)d_in[21];
  const float* qsa   = (const float*)d_in[24];
  const float* ksa   = (const float*)d_in[25];
  const float* s2w   = (const float*)d_in[27];
  float* out = (float*)d_out;
  char* wsb  = (char*)d_ws;

  // workspace layout (bytes)
  ushort* FB16 = (ushort*)(wsb);                 // 32768*128 bf16 = 8388608
  ushort* QB   = (ushort*)(wsb + 8388608);       // 131072 bf16
  ushort* KB2  = (ushort*)(wsb + 8650752);
  ushort* SB   = (ushort*)(wsb + 8912896);
  ushort* WL   = (ushort*)(wsb + 9175040);       // 98304 bf16
  ushort* WR   = (ushort*)(wsb + 9371648);
  float*  C1   = (float*)(wsb + 9568256);        // 128*128 f32
  float*  C2   = (float*)(wsb + 9633792);        // 128*256 f32
  float*  C3   = (float*)(wsb + 9764864);        // 128*128 f32
  float*  C4   = (float*)(wsb + 9830400);        // 128*128 f32

  prep_all_k<<<896, 256, 0, stream>>>(qsa, ksa, s2w,
                                      g1_wl, g2_wl, g3_wl, g4_wl,
                                      g1_wr, g2_wr, g3_wr, g4_wr,
                                      QB, KB2, SB, WL, WR);
  chain0_k<<<1, 256, 0, stream>>>(flows, WL, WR, g1_bl, g2_bl, g3_bl, C1, C2, C3, C4);
  sage_fused<<<512, 256, 0, stream>>>(flows, WR, g1_bl, g2_bl, g3_bl, g4_bl,
                                      C1, C2, C3, C4, FB16);
  attn_fused<<<256, 512, 0, stream>>>(FB16, QB, KB2, SB, out);
}